// Round 6
// baseline (861.908 us; speedup 1.0000x reference)
//
#include <hip/hip_runtime.h>
#include <hip/hip_bf16.h>

// Qwen3.5 attention block: T=4096, H=2048, NH=16, NKV=2, HD=256, ROT=64
// bf16 MFMA (16x16x32) with fp32 accumulate; precision-critical intermediates
// kept fp32 or split into bf16 hi/lo pairs (packed ushort2 in 4B slots).
// Attn: KV tile = 32 rows, LDS 37888B -> 3 blocks/CU, rotated prefetch.
// gemm_qg2 / gemm_out2: deep-pipeline 4-deep LDS ring, counted vmcnt (never 0
// mid-loop), 1 barrier per K-tile, XOR-swizzled staging (source-side) with
// matching read XOR, XCD n-panel grouping. gemm_out2 reads the packed hi/lo
// o-buffer DIRECTLY as interleaved bf16 (K'=8192) against a K-duplicated WoT
// image -> no A repack VALU at all.

#define T_SZ 4096
#define H_SZ 2048
#define NH_SZ 16
#define NKV_SZ 2
#define HD_SZ 256
#define ATT_SCALE 0.0625f   // HD^-0.5
#define SOFT_M 18.0f        // fixed softmax shift
#define EPS_ 1e-6f

typedef __attribute__((ext_vector_type(8))) short bf16x8;   // 8 bf16 = 4 VGPRs
typedef __attribute__((ext_vector_type(4))) float f32x4;

#define MFMA16(a, b, c) __builtin_amdgcn_mfma_f32_16x16x32_bf16((a), (b), (c), 0, 0, 0)

__device__ __forceinline__ void async16(const void* g, void* l) {
  __builtin_amdgcn_global_load_lds((const __attribute__((address_space(1))) void*)g,
                                   (__attribute__((address_space(3))) void*)l,
                                   16, 0, 0);
}

__device__ __forceinline__ float to_f(float x) { return x; }
__device__ __forceinline__ float to_f(__hip_bfloat16 x) { return __bfloat162float(x); }

union BfBits { __hip_bfloat16 h; unsigned short u; };

__device__ __forceinline__ unsigned short bf16_bits(__hip_bfloat16 h) {
  BfBits t; t.h = h; return t.u;
}

__device__ __forceinline__ unsigned pack_hilo(float v) {
  __hip_bfloat16 hi = __float2bfloat16(v);
  float rem = v - __bfloat162float(hi);
  __hip_bfloat16 lo = __float2bfloat16(rem);
  return (unsigned)bf16_bits(hi) | ((unsigned)bf16_bits(lo) << 16);
}

// ---------------------------------------------------------------- cast hidden
__global__ __launch_bounds__(256) void cast_f32_bf16(const float* __restrict__ in,
                                                     __hip_bfloat16* __restrict__ out,
                                                     int n4) {
  int i = blockIdx.x * 256 + threadIdx.x;
  if (i >= n4) return;
  float4 v = ((const float4*)in)[i];
  union { __hip_bfloat16 h[4]; uint2 u; } t;
  t.h[0] = __float2bfloat16(v.x);
  t.h[1] = __float2bfloat16(v.y);
  t.h[2] = __float2bfloat16(v.z);
  t.h[3] = __float2bfloat16(v.w);
  ((uint2*)out)[i] = t.u;
}

// ------------------------------------------------------- transpose (+cast bf16)
template <typename TIN>
__global__ __launch_bounds__(256) void transpose_cast(const TIN* __restrict__ in,
                                                      __hip_bfloat16* __restrict__ out,
                                                      int R, int C) {
  __shared__ TIN tile[32][33];
  int c0 = blockIdx.x * 32, r0 = blockIdx.y * 32;
  int tx = threadIdx.x & 31, ty = threadIdx.x >> 5;
#pragma unroll
  for (int i = 0; i < 32; i += 8)
    tile[ty + i][tx] = in[(long)(r0 + ty + i) * C + c0 + tx];
  __syncthreads();
#pragma unroll
  for (int i = 0; i < 32; i += 8)
    out[(long)(c0 + ty + i) * R + r0 + tx] = __float2bfloat16(to_f(tile[tx][ty + i]));
}

// -------------------- transpose Wo with K-duplication: out[n][k] = dup pair u32
// in: Wo (R=4096 k-rows, C=2048 n-cols) fp32. out: (2048 n rows, 4096 u32 cols),
// each u32 = bf16(Wo[k,n]) duplicated in both halves -> bf16 (2048, 8192) image.
__global__ __launch_bounds__(256) void transpose_dup(const float* __restrict__ in,
                                                     unsigned* __restrict__ out,
                                                     int R, int C) {
  __shared__ float tile[32][33];
  int c0 = blockIdx.x * 32, r0 = blockIdx.y * 32;
  int tx = threadIdx.x & 31, ty = threadIdx.x >> 5;
#pragma unroll
  for (int i = 0; i < 32; i += 8)
    tile[ty + i][tx] = in[(long)(r0 + ty + i) * C + c0 + tx];
  __syncthreads();
#pragma unroll
  for (int i = 0; i < 32; i += 8) {
    unsigned short b = bf16_bits(__float2bfloat16(tile[tx][ty + i]));
    out[(long)(c0 + ty + i) * R + r0 + tx] = (unsigned)b | ((unsigned)b << 16);
  }
}

// ---------------- Wq GEMM, deep-pipelined: q(fp32)/gate(bf16) split epilogue
// 256x256 tile, BK=32, 4-deep LDS ring, counted vmcnt, quad-XOR LDS swizzle.
__global__ __launch_bounds__(512) void gemm_qg2(const __hip_bfloat16* __restrict__ A,
                                                const __hip_bfloat16* __restrict__ BT,
                                                float* __restrict__ qout,
                                                __hip_bfloat16* __restrict__ gate) {
  __shared__ __align__(16) __hip_bfloat16 As[4][8192];  // [buf][kcslot 4][row 256][e 8]
  __shared__ __align__(16) __hip_bfloat16 Bs[4][8192];
  const int tid = threadIdx.x, wid = tid >> 6, lane = tid & 63;
  const int lo = lane & 15, quad = lane >> 4;
  const int wm = (wid >> 2) * 128, wn = (wid & 3) * 64;  // 2m x 4n waves
  const int wg = blockIdx.x + blockIdx.y * 8;            // 512 wgs
  const int xcd = wg & 7, i_ = wg >> 3;                  // i_ in [0,64)
  const long n0 = (long)(xcd * 4 + (i_ & 3)) * 256;      // 4 B-panels (4MB) per XCD
  const long m0 = (long)(i_ >> 2) * 256;
  const int K = 2048;

  const int r0_ = tid >> 2;                       // rows 0..127 (load0), +128 (load1)
  const int kc0 = (tid & 3) ^ ((tid >> 3) & 3);   // slot ^ ((row>>1)&3)
  const __hip_bfloat16* sA0 = A + (m0 + r0_) * K + kc0 * 8;
  const __hip_bfloat16* sA1 = A + (m0 + r0_ + 128) * K + kc0 * 8;
  const __hip_bfloat16* sB0 = BT + (n0 + r0_) * K + kc0 * 8;
  const __hip_bfloat16* sB1 = BT + (n0 + r0_ + 128) * K + kc0 * 8;

  const int xq = (lo >> 1) & 3;
  const int aoff = (wm + lo) * 32 + ((quad ^ xq) * 8);
  const int boff = (wn + lo) * 32 + ((quad ^ xq) * 8);

  const f32x4 z4 = {0.f, 0.f, 0.f, 0.f};
  f32x4 acc[8][4];
#pragma unroll
  for (int fr = 0; fr < 8; ++fr)
#pragma unroll
    for (int fn = 0; fn < 4; ++fn) acc[fr][fn] = z4;

#define QG_STAGE(buf, kt) do {                                   \
    const int off_ = (kt) * 32;                                  \
    async16(sA0 + off_, &As[buf][tid * 8]);                      \
    async16(sA1 + off_, &As[buf][tid * 8 + 4096]);               \
    async16(sB0 + off_, &Bs[buf][tid * 8]);                      \
    async16(sB1 + off_, &Bs[buf][tid * 8 + 4096]);               \
  } while (0)

#define QG_COMPUTE(buf_) do {                                    \
    bf16x8 af[8], bq[4];                                         \
    _Pragma("unroll")                                            \
    for (int fr = 0; fr < 8; ++fr)                               \
      af[fr] = *(const bf16x8*)(&As[buf_][aoff + fr * 512]);     \
    _Pragma("unroll")                                            \
    for (int fn = 0; fn < 4; ++fn)                               \
      bq[fn] = *(const bf16x8*)(&Bs[buf_][boff + fn * 512]);     \
    __builtin_amdgcn_s_setprio(1);                               \
    _Pragma("unroll")                                            \
    for (int fr = 0; fr < 8; ++fr)                               \
      _Pragma("unroll")                                          \
      for (int fn = 0; fn < 4; ++fn)                             \
        acc[fr][fn] = MFMA16(af[fr], bq[fn], acc[fr][fn]);       \
    __builtin_amdgcn_s_setprio(0);                               \
  } while (0)

  QG_STAGE(0, 0); QG_STAGE(1, 1); QG_STAGE(2, 2);
  for (int kt = 0; kt < 61; ++kt) {
    asm volatile("s_waitcnt vmcnt(8)" ::: "memory");
    __builtin_amdgcn_s_barrier();
    __builtin_amdgcn_sched_barrier(0);
    QG_STAGE((kt + 3) & 3, kt + 3);
    __builtin_amdgcn_sched_barrier(0);
    QG_COMPUTE(kt & 3);
  }
  asm volatile("s_waitcnt vmcnt(8)" ::: "memory");
  __builtin_amdgcn_s_barrier();
  __builtin_amdgcn_sched_barrier(0);
  QG_COMPUTE(1);   // kt=61
  asm volatile("s_waitcnt vmcnt(4)" ::: "memory");
  __builtin_amdgcn_s_barrier();
  __builtin_amdgcn_sched_barrier(0);
  QG_COMPUTE(2);   // kt=62
  asm volatile("s_waitcnt vmcnt(0)" ::: "memory");
  __builtin_amdgcn_s_barrier();
  __builtin_amdgcn_sched_barrier(0);
  QG_COMPUTE(3);   // kt=63
#undef QG_STAGE
#undef QG_COMPUTE

#pragma unroll
  for (int fr = 0; fr < 8; ++fr)
#pragma unroll
    for (int fn = 0; fn < 4; ++fn)
#pragma unroll
      for (int rr = 0; rr < 4; ++rr) {
        long row = m0 + wm + fr * 16 + quad * 4 + rr;  // token t
        long col = n0 + wn + fn * 16 + lo;             // n in [0,8192)
        int head = (int)(col >> 9), c = (int)(col & 511);
        float v = acc[fr][fn][rr];
        if (c < 256)
          qout[(row * NH_SZ + head) * 256 + c] = v;
        else
          gate[(row * NH_SZ + head) * 256 + (c - 256)] = __float2bfloat16(v);
      }
}

// ---------------- out GEMM, deep-pipelined (qg2 clone at K'=8192):
// A = packed hi/lo o-buffer viewed as interleaved bf16 (4096, 8192), async16'd
// directly (no repack). B = K-duplicated WoT image (2048, 8192) bf16.
// BM=256, BN=128, BK=32 -> grid 256 blocks (all CUs). 4-deep ring, vmcnt(6),
// 1 barrier/K-tile. XCD grouping: 2 n-panels (4MB) per XCD L2. C fp32 out.
__global__ __launch_bounds__(512) void gemm_out2(const __hip_bfloat16* __restrict__ A,
                                                 const __hip_bfloat16* __restrict__ BT,
                                                 float* __restrict__ C) {
  __shared__ __align__(16) __hip_bfloat16 As[4][8192];  // [buf][row 256][32]
  __shared__ __align__(16) __hip_bfloat16 Bs[4][4096];  // [buf][row 128][32]
  const int tid = threadIdx.x, wid = tid >> 6, lane = tid & 63;
  const int lo = lane & 15, quad = lane >> 4;
  const int wm = (wid >> 1) * 64, wn = (wid & 1) * 64;   // 4m x 2n waves
  const int wg = blockIdx.x + blockIdx.y * 8;            // 256 wgs
  const int xcd = wg & 7, i_ = wg >> 3;                  // i_ in [0,32)
  const long n0 = (long)(xcd * 2 + (i_ & 1)) * 128;      // 2 B-panels (4MB) per XCD
  const long m0 = (long)(i_ >> 1) * 256;
  const long Kp = 8192;

  // staging: slot s -> (row=s>>2, sp=s&3); source k-slot XOR'd with row&3
  const int rA = tid >> 2, spx = (tid & 3) ^ ((tid >> 2) & 3);
  const __hip_bfloat16* sA0 = A + (m0 + rA) * Kp + spx * 8;
  const __hip_bfloat16* sA1 = A + (m0 + rA + 128) * Kp + spx * 8;  // (row+128)&3 == row&3
  const __hip_bfloat16* sB0 = BT + (n0 + rA) * Kp + spx * 8;       // rows 0..127

  // read side: same XOR; row&3 == lo&3 (wm/wn, fr*16 are multiples of 4)
  const int xa = quad ^ (lo & 3);
  const int aoff = (wm + lo) * 32 + xa * 8;
  const int boff = (wn + lo) * 32 + xa * 8;

  const f32x4 z4 = {0.f, 0.f, 0.f, 0.f};
  f32x4 acc[4][4];
#pragma unroll
  for (int fr = 0; fr < 4; ++fr)
#pragma unroll
    for (int fn = 0; fn < 4; ++fn) acc[fr][fn] = z4;

#define GO_STAGE(buf, kt) do {                                   \
    const long off_ = (long)(kt) * 32;                           \
    async16(sA0 + off_, &As[buf][tid * 8]);                      \
    async16(sA1 + off_, &As[buf][tid * 8 + 4096]);               \
    async16(sB0 + off_, &Bs[buf][tid * 8]);                      \
  } while (0)

#define GO_COMPUTE(buf_) do {                                    \
    bf16x8 af[4], bq[4];                                         \
    _Pragma("unroll")                                            \
    for (int fr = 0; fr < 4; ++fr)                               \
      af[fr] = *(const bf16x8*)(&As[buf_][aoff + fr * 512]);     \
    _Pragma("unroll")                                            \
    for (int fn = 0; fn < 4; ++fn)                               \
      bq[fn] = *(const bf16x8*)(&Bs[buf_][boff + fn * 512]);     \
    __builtin_amdgcn_s_setprio(1);                               \
    _Pragma("unroll")                                            \
    for (int fr = 0; fr < 4; ++fr)                               \
      _Pragma("unroll")                                          \
      for (int fn = 0; fn < 4; ++fn)                             \
        acc[fr][fn] = MFMA16(af[fr], bq[fn], acc[fr][fn]);       \
    __builtin_amdgcn_s_setprio(0);                               \
  } while (0)

  // 256 K-tiles; 3-op stages -> in-flight 3 tiles = 9 ops, wait to 6
  GO_STAGE(0, 0); GO_STAGE(1, 1); GO_STAGE(2, 2);
  for (int kt = 0; kt < 253; ++kt) {
    asm volatile("s_waitcnt vmcnt(6)" ::: "memory");
    __builtin_amdgcn_s_barrier();
    __builtin_amdgcn_sched_barrier(0);
    GO_STAGE((kt + 3) & 3, kt + 3);
    __builtin_amdgcn_sched_barrier(0);
    GO_COMPUTE(kt & 3);
  }
  asm volatile("s_waitcnt vmcnt(6)" ::: "memory");
  __builtin_amdgcn_s_barrier();
  __builtin_amdgcn_sched_barrier(0);
  GO_COMPUTE(1);   // kt=253
  asm volatile("s_waitcnt vmcnt(3)" ::: "memory");
  __builtin_amdgcn_s_barrier();
  __builtin_amdgcn_sched_barrier(0);
  GO_COMPUTE(2);   // kt=254
  asm volatile("s_waitcnt vmcnt(0)" ::: "memory");
  __builtin_amdgcn_s_barrier();
  __builtin_amdgcn_sched_barrier(0);
  GO_COMPUTE(3);   // kt=255
#undef GO_STAGE
#undef GO_COMPUTE

#pragma unroll
  for (int fr = 0; fr < 4; ++fr)
#pragma unroll
    for (int fn = 0; fn < 4; ++fn)
#pragma unroll
      for (int rr = 0; rr < 4; ++rr) {
        long row = m0 + wm + fr * 16 + quad * 4 + rr;
        long col = n0 + wn + fn * 16 + lo;
        C[row * 2048 + col] = acc[fr][fn][rr];
      }
}

// --------------------------- fused K+V projection GEMM (N=1024; WkT||WvT rows)
__global__ __launch_bounds__(256) void gemm_kv(const __hip_bfloat16* __restrict__ A,
                                               const __hip_bfloat16* __restrict__ BT,
                                               float* __restrict__ kf,
                                               __hip_bfloat16* __restrict__ vraw,
                                               int M, int N, int K) {
  __shared__ __align__(16) __hip_bfloat16 As[128 * 32];
  __shared__ __align__(16) __hip_bfloat16 Bs[128 * 32];
  const int tid = threadIdx.x;
  const int wid = tid >> 6, lane = tid & 63;
  const int lo = lane & 15, quad = lane >> 4;
  const int wq = blockIdx.x + blockIdx.y * 8;    // nwg = 256
  const int xcd = wq & 7, idx = wq >> 3;         // idx in [0,32)
  const long n0 = (long)xcd * 128;
  const long m0 = (long)idx * 128;
  const int wm = (wid >> 1) * 64, wn = (wid & 1) * 64;
  const f32x4 z4 = {0.f, 0.f, 0.f, 0.f};
  f32x4 acc[4][4];
#pragma unroll
  for (int i = 0; i < 4; ++i)
#pragma unroll
    for (int j = 0; j < 4; ++j) acc[i][j] = z4;

  const int cf0 = tid, cf1 = 256 + tid;
  const int r0_ = cf0 >> 2, c0_ = (cf0 & 3) * 8;
  const int r1_ = cf1 >> 2, c1_ = (cf1 & 3) * 8;
  const __hip_bfloat16* a0 = A + (m0 + r0_) * K + c0_;
  const __hip_bfloat16* a1 = A + (m0 + r1_) * K + c1_;
  const __hip_bfloat16* b0 = BT + (n0 + r0_) * K + c0_;
  const __hip_bfloat16* b1 = BT + (n0 + r1_) * K + c1_;

  for (int k0 = 0; k0 < K; k0 += 32) {
    async16(a0 + k0, As + cf0 * 8);
    async16(a1 + k0, As + cf1 * 8);
    async16(b0 + k0, Bs + cf0 * 8);
    async16(b1 + k0, Bs + cf1 * 8);
    __syncthreads();
    bf16x8 af[4], bfv[4];
#pragma unroll
    for (int i = 0; i < 4; ++i)
      af[i] = *(const bf16x8*)(As + (wm + i * 16 + lo) * 32 + quad * 8);
#pragma unroll
    for (int i = 0; i < 4; ++i)
      bfv[i] = *(const bf16x8*)(Bs + (wn + i * 16 + lo) * 32 + quad * 8);
#pragma unroll
    for (int i = 0; i < 4; ++i)
#pragma unroll
      for (int j = 0; j < 4; ++j) acc[i][j] = MFMA16(af[i], bfv[j], acc[i][j]);
    __syncthreads();
  }
#pragma unroll
  for (int i = 0; i < 4; ++i)
#pragma unroll
    for (int j = 0; j < 4; ++j)
#pragma unroll
      for (int r = 0; r < 4; ++r) {
        long row = m0 + wm + i * 16 + quad * 4 + r;
        long col = n0 + wn + j * 16 + lo;          // [0,1024)
        float v = acc[i][j][r];
        if (col < 512)
          kf[row * 512 + col] = v;
        else
          vraw[row * 512 + (col - 512)] = __float2bfloat16(v);
      }
}

// --------------------------------------- V -> swizzled LDS-image layout
__global__ __launch_bounds__(256) void v_swizzle(const __hip_bfloat16* __restrict__ vraw,
                                                 __hip_bfloat16* __restrict__ vsw) {
  const int ktt = blockIdx.x, kvh = blockIdx.y, tid = threadIdx.x;
  __shared__ __hip_bfloat16 L[64 * 264];
#pragma unroll
  for (int it = 0; it < 8; ++it) {
    int cf = it * 256 + tid;           // 2048 chunks of 8 elems
    int kv = cf >> 5, d0 = (cf & 31) * 8;
    *(uint4*)&L[kv * 264 + d0] =
        *(const uint4*)&vraw[(((long)ktt * 64 + kv) * NKV_SZ + kvh) * 256 + d0];
  }
  __syncthreads();
#pragma unroll
  for (int it = 0; it < 8; ++it) {
    int cf = it * 256 + tid;           // c in [0,8), d in [0,256)
    int c = cf >> 8, d = cf & 255;
    union { __hip_bfloat16 h[8]; uint4 u; } t;
#pragma unroll
    for (int e = 0; e < 8; ++e) t.h[e] = L[(c * 8 + e) * 264 + d];
    *(uint4*)&vsw[((long)kvh * 64 + ktt) * 16384 + (long)(c * 256 + d) * 8] = t.u;
  }
}

// ---- RMSNorm + RoPE, wave-per-row (no LDS, no barriers). 4 rows per block.
__global__ __launch_bounds__(256) void norm_rope_wave(float* __restrict__ qbuf,
                                                      const float* __restrict__ kbuf,
                                                      __hip_bfloat16* __restrict__ ksw,
                                                      const int* __restrict__ pos,
                                                      const float* __restrict__ qw,
                                                      const float* __restrict__ kw) {
  const int id = blockIdx.x * 4 + (threadIdx.x >> 6);   // row id in [0, 4096*18)
  const int lane = threadIdx.x & 63;
  const int h = id % 18, t = id / 18;
  const bool isq = h < NH_SZ;
  const float* ptr = isq ? qbuf + ((long)t * NH_SZ + h) * 256
                         : kbuf + ((long)t * NKV_SZ + (h - NH_SZ)) * 256;
  const float* w = isq ? qw : kw;
  float4 v = *(const float4*)(ptr + lane * 4);   // d = lane*4 + j
  float4 wv = *(const float4*)(w + lane * 4);
  float s2 = v.x * v.x + v.y * v.y + v.z * v.z + v.w * v.w;
#pragma unroll
  for (int o = 32; o > 0; o >>= 1) s2 += __shfl_xor(s2, o);
  float sc = rsqrtf(s2 * (1.0f / 256.0f) + EPS_);
  float n[4];
  n[0] = v.x * sc * (1.0f + wv.x);
  n[1] = v.y * sc * (1.0f + wv.y);
  n[2] = v.z * sc * (1.0f + wv.z);
  n[3] = v.w * sc * (1.0f + wv.w);
  float pr[4];
#pragma unroll
  for (int j = 0; j < 4; ++j) pr[j] = __shfl_xor(n[j], 8);
  float o4[4];
  if (lane < 16) {
    int base_i = (lane & 7) * 4;
#pragma unroll
    for (int j = 0; j < 4; ++j) {
      int i = base_i + j;
      float p = (float)pos[(i % 3) * T_SZ + t];
      float fr = p * exp2f((float)i * (-0.72667177075661f));  // 1e7^(-i/32)
      float c, s;
      sincosf(fr, &s, &c);
      o4[j] = (lane < 8) ? n[j] * c - pr[j] * s : n[j] * c + pr[j] * s;
    }
  } else {
#pragma unroll
    for (int j = 0; j < 4; ++j) o4[j] = n[j];
  }
  if (isq) {
    uint4 u;
    u.x = pack_hilo(o4[0]); u.y = pack_hilo(o4[1]);
    u.z = pack_hilo(o4[2]); u.w = pack_hilo(o4[3]);
    *(uint4*)((unsigned*)qbuf + ((long)t * NH_SZ + h) * 256 + lane * 4) = u;
  } else {
    int kv = h - NH_SZ;
    long tt = t >> 5; int r = t & 31;
    int c = lane >> 1, e0 = (lane & 1) * 4;
    union { __hip_bfloat16 h4[4]; uint2 u; } kk;
#pragma unroll
    for (int j = 0; j < 4; ++j) kk.h4[j] = __float2bfloat16(o4[j]);
    *(uint2*)&ksw[(((long)kv * 128 + tt) * 32 + c) * 256 + r * 8 + e0] = kk.u;
  }
}

// ------------------------------------------------------- flash causal attention
__global__ __launch_bounds__(256) void attn_kernel(unsigned* __restrict__ Qp,
                                                   const __hip_bfloat16* __restrict__ Ksw,
                                                   const __hip_bfloat16* __restrict__ Vsw,
                                                   const __hip_bfloat16* __restrict__ Gt) {
  const int w = blockIdx.x + blockIdx.y * 64;
  const int xcd = w & 7, j = w >> 3;           // j in [0,128)
  const int h = xcd * 2 + (j & 1);
  const int qt = 63 - (j >> 1);
  const int kvh = h >> 3;
  const int tid = threadIdx.x, wid = tid >> 6, lane = tid & 63;
  const int lo = lane & 15, quad = lane >> 4;
  __shared__ __align__(16) __hip_bfloat16 Ks[32 * 256];   // [c=d/8][r=kv%32][e]
  __shared__ __align__(16) __hip_bfloat16 Vs[4 * 2048];   // [cc=kv/8][d=256][e]
  __shared__ __align__(16) __hip_bfloat16 Ps[4][16 * 40]; // per-wave 16x32, stride 40

  __hip_bfloat16* myP = &Ps[wid][0];
  const f32x4 z4 = {0.f, 0.f, 0.f, 0.f};
  const int nt = 2 * (qt + 1);                 // 32-row KV tiles

  bf16x8 qh[8], ql[8];
  {
    const unsigned* qp =
        Qp + ((long)(qt * 64 + wid * 16 + lo) * NH_SZ + h) * 256 + quad * 8;
#pragma unroll
    for (int kc = 0; kc < 8; ++kc) {
      uint4 p0 = *(const uint4*)(qp + kc * 32);
      uint4 p1 = *(const uint4*)(qp + kc * 32 + 4);
      bf16x8 a, b;
      a[0] = (short)(p0.x & 0xffff); b[0] = (short)(p0.x >> 16);
      a[1] = (short)(p0.y & 0xffff); b[1] = (short)(p0.y >> 16);
      a[2] = (short)(p0.z & 0xffff); b[2] = (short)(p0.z >> 16);
      a[3] = (short)(p0.w & 0xffff); b[3] = (short)(p0.w >> 16);
      a[4] = (short)(p1.x & 0xffff); b[4] = (short)(p1.x >> 16);
      a[5] = (short)(p1.y & 0xffff); b[5] = (short)(p1.y >> 16);
      a[6] = (short)(p1.z & 0xffff); b[6] = (short)(p1.z >> 16);
      a[7] = (short)(p1.w & 0xffff); b[7] = (short)(p1.w >> 16);
      qh[kc] = a; ql[kc] = b;
    }
  }

  f32x4 acc[16];
#pragma unroll
  for (int od = 0; od < 16; ++od) acc[od] = z4;
  float lsum[4];
#pragma unroll
  for (int r = 0; r < 4; ++r) lsum[r] = 0.f;

  const int qrow_g = qt * 64 + wid * 16 + quad * 4;
  const __hip_bfloat16* kbase = Ksw + (long)kvh * 1048576;  // 128 tiles * 8192
  const __hip_bfloat16* vbase = Vsw + (long)kvh * 1048576;

#pragma unroll
  for (int i = 0; i < 4; ++i) {
    int m = i * 4 + wid;
    async16(kbase + m * 512 + lane * 8, Ks + m * 512 + lane * 8);
    async16(vbase + m * 512 + lane * 8, Vs + m * 512 + lane * 8);
  }
  __syncthreads();  // drain K(0), V(0)

  for (int kt = 0; kt < nt; ++kt) {
    const bool skip = (kt == nt - 1) && (wid < 2);
    f32x4 s[2];
    s[0] = z4; s[1] = z4;
    if (!skip) {
      __builtin_amdgcn_s_setprio(1);
#pragma unroll
      for (int kc = 0; kc < 8; ++kc) {
        bf16x8 ah = qh[kc], al = ql[kc];
#pragma unroll
        for (int ni = 0; ni < 2; ++ni) {
          bf16x8 b = *(const bf16x8*)(Ks + (kc * 4 + quad) * 256 + (ni * 16 + lo) * 8);
          s[ni] = MFMA16(ah, b, s[ni]);
          s[ni] = MFMA16(al, b, s[ni]);
        }
      }
      __builtin_amdgcn_s_setprio(0);
    }
    __syncthreads();  // B: Ks(kt) reads done; drains V(kt) prefetch
    if (kt + 1 < nt) {
      const __hip_bfloat16* kb = kbase + (long)(kt + 1) * 8192;
#pragma unroll
      for (int i = 0; i < 4; ++i) {
        int m = i * 4 + wid;
        async16(kb + m * 512 + lane * 8, Ks + m * 512 + lane * 8);
      }
    }
    if (!skip) {
      float sv[2][4];
      if (kt >= nt - 2) {
#pragma unroll
        for (int ni = 0; ni < 2; ++ni) {
          int kcol = kt * 32 + ni * 16 + lo;
#pragma unroll
          for (int r = 0; r < 4; ++r) {
            float e = __expf(fmaf(s[ni][r], ATT_SCALE, -SOFT_M));
            sv[ni][r] = (kcol > qrow_g + r) ? 0.f : e;
          }
        }
      } else {
#pragma unroll
        for (int ni = 0; ni < 2; ++ni)
#pragma unroll
          for (int r = 0; r < 4; ++r)
            sv[ni][r] = __expf(fmaf(s[ni][r], ATT_SCALE, -SOFT_M));
      }
#pragma unroll
      for (int r = 0; r < 4; ++r) lsum[r] += sv[0][r] + sv[1][r];
#pragma unroll
      for (int ni = 0; ni < 2; ++ni)
#pragma unroll
        for (int r = 0; r < 4; ++r)
          myP[(quad * 4 + r) * 40 + ni * 16 + lo] = __float2bfloat16(sv[ni][r]);
      bf16x8 ap = *(const bf16x8*)(myP + lo * 40 + quad * 8);
      __builtin_amdgcn_s_setprio(1);
#pragma unroll
      for (int od = 0; od < 16; ++od) {
        bf16x8 bv = *(const bf16x8*)(Vs + quad * 2048 + (od * 16 + lo) * 8);
        acc[od] = MFMA16(ap, bv, acc[od]);
      }
      __builtin_amdgcn_s_setprio(0);
    }
    __syncthreads();  // C: Vs(kt) reads done; drains K(kt+1) prefetch
    if (kt + 1 < nt) {
      const __hip_bfloat16* vb = vbase + (long)(kt + 1) * 8192;
#pragma unroll
      for (int i = 0; i < 4; ++i) {
        int m = i * 4 + wid;
        async16(vb + m * 512 + lane * 8, Vs + m * 512 + lane * 8);
      }
    }
  }

  float l_r[4];
#pragma unroll
  for (int r = 0; r < 4; ++r) {
    float su = lsum[r];
#pragma unroll
    for (int off = 1; off < 16; off <<= 1) su += __shfl_xor(su, off);
    l_r[r] = su;
  }
#pragma unroll
  for (int od = 0; od < 16; ++od)
#pragma unroll
    for (int r = 0; r < 4; ++r) {
      int trow = qt * 64 + wid * 16 + quad * 4 + r;
      int col = od * 16 + lo;
      long idx = ((long)trow * NH_SZ + h) * 256 + col;
      float g = __bfloat162float(Gt[idx]);
      float sig = 1.0f / (1.0f + expf(-g));
      float v = (acc[od][r] / l_r[r]) * sig;
      Qp[idx] = pack_hilo(v);
    }
}

// ------------------------------------------------------------------- launcher
extern "C" void kernel_launch(void* const* d_in, const int* in_sizes, int n_in,
                              void* d_out, int out_size, void* d_ws, size_t ws_size,
                              hipStream_t stream) {
  (void)in_sizes; (void)n_in; (void)out_size; (void)ws_size;
  const int* positions = (const int*)d_in[0];
  const float* hidden = (const float*)d_in[1];
  const float* Wq = (const float*)d_in[2];
  const float* Wk = (const float*)d_in[3];
  const float* Wv = (const float*)d_in[4];
  const float* Wo = (const float*)d_in[5];
  const float* qw = (const float*)d_in[6];
  const float* kw = (const float*)d_in[7];
  float* out = (float*)d_out;
  char* ws = (char*)d_ws;

  // layout (bytes), total exactly 160 MiB:
  __hip_bfloat16* hid  = (__hip_bfloat16*)(ws + 0);           // 16 MB (dead after GEMMs)
  __hip_bfloat16* WqT  = (__hip_bfloat16*)(ws + 16777216);    // 32 MB (dead after gemm_qg2)
  __hip_bfloat16* WkT  = (__hip_bfloat16*)(ws + 50331648);    //  2 MB  (WvT contiguous after)
  __hip_bfloat16* WvT  = (__hip_bfloat16*)(ws + 52428800);    //  2 MB
  float*          qf   = (float*)(ws + 54525952);             // 64 MB fp32 q -> packed -> o packed
  __hip_bfloat16* gate = (__hip_bfloat16*)(ws + 121634816);   // 32 MB (T,16,256)
  float*          kf   = (float*)(ws + 155189248);            //  8 MB (T,2,256) fp32
  __hip_bfloat16* vraw = (__hip_bfloat16*)(ws + 163577856);   //  4 MB -> end 167,772,160
  __hip_bfloat16* Ksw  = WkT;                                  // alias 4 MB [WkT+WvT] after kv GEMM
  __hip_bfloat16* Vsw  = hid;                                  // alias 4 MB of hid after GEMMs
  unsigned*       Wo2  = (unsigned*)WqT;                       // alias 32 MB: K-dup WoT image
  unsigned* qpk = (unsigned*)qf;

  // 1) casts / transposes
  cast_f32_bf16<<<dim3(8192), dim3(256), 0, stream>>>(hidden, hid, 2097152);
  transpose_cast<float><<<dim3(256, 64), dim3(256), 0, stream>>>(Wq, WqT, 2048, 8192);
  transpose_cast<float><<<dim3(16, 64), dim3(256), 0, stream>>>(Wk, WkT, 2048, 512);
  transpose_cast<float><<<dim3(16, 64), dim3(256), 0, stream>>>(Wv, WvT, 2048, 512);
  // 2) projections: q fp32 + gate bf16 (deep-pipelined 256^2); fused k/v
  gemm_qg2<<<dim3(8, 64), dim3(512), 0, stream>>>(hid, WqT, qf, gate);
  gemm_kv<<<dim3(8, 32), dim3(256), 0, stream>>>(hid, WkT, kf, vraw, 4096, 1024, 2048);
  // 3) V -> swizzled (after GEMMs: Vsw aliases hid)
  v_swizzle<<<dim3(64, 2), dim3(256), 0, stream>>>(vraw, Vsw);
  // 4) RMSNorm + RoPE, wave-per-row: q packed in-place; k swizzled -> Ksw
  norm_rope_wave<<<dim3(18432), dim3(256), 0, stream>>>(qf, kf, Ksw, positions, qw, kw);
  // 5) flash attention, one q-tile per block, big-first + XCD swizzle
  attn_kernel<<<dim3(64, 16), dim3(256), 0, stream>>>(qpk, Ksw, Vsw, gate);
  // 6) Wo -> K-dup bf16 image (into dead WqT), then deep-pipelined out GEMM:
  //    packed o-buffer read directly as interleaved bf16 (no repack).
  transpose_dup<<<dim3(64, 128), dim3(256), 0, stream>>>(Wo, Wo2, 4096, 2048);
  gemm_out2<<<dim3(8, 32), dim3(512), 0, stream>>>((const __hip_bfloat16*)qpk,
                                                   (const __hip_bfloat16*)Wo2, out);
}

// Round 7
// 828.159 us; speedup vs baseline: 1.0408x; 1.0408x over previous
//
#include <hip/hip_runtime.h>
#include <hip/hip_bf16.h>

// Qwen3.5 attention block: T=4096, H=2048, NH=16, NKV=2, HD=256, ROT=64
// bf16 MFMA (16x16x32) with fp32 accumulate; precision-critical intermediates
// kept fp32 or split into bf16 hi/lo pairs (packed ushort2 in 4B slots).
// Attn: KV tile = 32 rows, LDS 37888B -> 3 blocks/CU, rotated prefetch.
// gemm_qg2 / gemm_out2: deep-pipeline LDS ring, counted vmcnt (never 0
// mid-loop), 1 barrier per K-tile, XOR-swizzled staging + matching read XOR,
// XCD n-panel grouping. gemm_out2 reads the packed hi/lo o-buffer DIRECTLY as
// interleaved bf16 (K'=8192) vs a K-duplicated WoT image (no A repack VALU).
// Round-7 fix: gemm_out2 BK=64 (two qg2-layout 32-col sub-tiles per K-tile,
// 3-deep ring, 144KB LDS) -> 32 MFMA/wave/barrier, 128 K-tiles (same
// amortization ratio as the validated gemm_qg2).

#define T_SZ 4096
#define H_SZ 2048
#define NH_SZ 16
#define NKV_SZ 2
#define HD_SZ 256
#define ATT_SCALE 0.0625f   // HD^-0.5
#define SOFT_M 18.0f        // fixed softmax shift
#define EPS_ 1e-6f

typedef __attribute__((ext_vector_type(8))) short bf16x8;   // 8 bf16 = 4 VGPRs
typedef __attribute__((ext_vector_type(4))) float f32x4;

#define MFMA16(a, b, c) __builtin_amdgcn_mfma_f32_16x16x32_bf16((a), (b), (c), 0, 0, 0)

__device__ __forceinline__ void async16(const void* g, void* l) {
  __builtin_amdgcn_global_load_lds((const __attribute__((address_space(1))) void*)g,
                                   (__attribute__((address_space(3))) void*)l,
                                   16, 0, 0);
}

__device__ __forceinline__ float to_f(float x) { return x; }
__device__ __forceinline__ float to_f(__hip_bfloat16 x) { return __bfloat162float(x); }

union BfBits { __hip_bfloat16 h; unsigned short u; };

__device__ __forceinline__ unsigned short bf16_bits(__hip_bfloat16 h) {
  BfBits t; t.h = h; return t.u;
}

__device__ __forceinline__ unsigned pack_hilo(float v) {
  __hip_bfloat16 hi = __float2bfloat16(v);
  float rem = v - __bfloat162float(hi);
  __hip_bfloat16 lo = __float2bfloat16(rem);
  return (unsigned)bf16_bits(hi) | ((unsigned)bf16_bits(lo) << 16);
}

// ---------------------------------------------------------------- cast hidden
__global__ __launch_bounds__(256) void cast_f32_bf16(const float* __restrict__ in,
                                                     __hip_bfloat16* __restrict__ out,
                                                     int n4) {
  int i = blockIdx.x * 256 + threadIdx.x;
  if (i >= n4) return;
  float4 v = ((const float4*)in)[i];
  union { __hip_bfloat16 h[4]; uint2 u; } t;
  t.h[0] = __float2bfloat16(v.x);
  t.h[1] = __float2bfloat16(v.y);
  t.h[2] = __float2bfloat16(v.z);
  t.h[3] = __float2bfloat16(v.w);
  ((uint2*)out)[i] = t.u;
}

// ------------------------------------------------------- transpose (+cast bf16)
template <typename TIN>
__global__ __launch_bounds__(256) void transpose_cast(const TIN* __restrict__ in,
                                                      __hip_bfloat16* __restrict__ out,
                                                      int R, int C) {
  __shared__ TIN tile[32][33];
  int c0 = blockIdx.x * 32, r0 = blockIdx.y * 32;
  int tx = threadIdx.x & 31, ty = threadIdx.x >> 5;
#pragma unroll
  for (int i = 0; i < 32; i += 8)
    tile[ty + i][tx] = in[(long)(r0 + ty + i) * C + c0 + tx];
  __syncthreads();
#pragma unroll
  for (int i = 0; i < 32; i += 8)
    out[(long)(c0 + ty + i) * R + r0 + tx] = __float2bfloat16(to_f(tile[tx][ty + i]));
}

// -------------------- transpose Wo with K-duplication: out[n][k] = dup pair u32
__global__ __launch_bounds__(256) void transpose_dup(const float* __restrict__ in,
                                                     unsigned* __restrict__ out,
                                                     int R, int C) {
  __shared__ float tile[32][33];
  int c0 = blockIdx.x * 32, r0 = blockIdx.y * 32;
  int tx = threadIdx.x & 31, ty = threadIdx.x >> 5;
#pragma unroll
  for (int i = 0; i < 32; i += 8)
    tile[ty + i][tx] = in[(long)(r0 + ty + i) * C + c0 + tx];
  __syncthreads();
#pragma unroll
  for (int i = 0; i < 32; i += 8) {
    unsigned short b = bf16_bits(__float2bfloat16(tile[tx][ty + i]));
    out[(long)(c0 + ty + i) * R + r0 + tx] = (unsigned)b | ((unsigned)b << 16);
  }
}

// ---------------- Wq GEMM, deep-pipelined: q(fp32)/gate(bf16) split epilogue
// 256x256 tile, BK=32, 4-deep LDS ring, counted vmcnt, quad-XOR LDS swizzle.
__global__ __launch_bounds__(512) void gemm_qg2(const __hip_bfloat16* __restrict__ A,
                                                const __hip_bfloat16* __restrict__ BT,
                                                float* __restrict__ qout,
                                                __hip_bfloat16* __restrict__ gate) {
  __shared__ __align__(16) __hip_bfloat16 As[4][8192];  // [buf][kcslot 4][row 256][e 8]
  __shared__ __align__(16) __hip_bfloat16 Bs[4][8192];
  const int tid = threadIdx.x, wid = tid >> 6, lane = tid & 63;
  const int lo = lane & 15, quad = lane >> 4;
  const int wm = (wid >> 2) * 128, wn = (wid & 3) * 64;  // 2m x 4n waves
  const int wg = blockIdx.x + blockIdx.y * 8;            // 512 wgs
  const int xcd = wg & 7, i_ = wg >> 3;                  // i_ in [0,64)
  const long n0 = (long)(xcd * 4 + (i_ & 3)) * 256;      // 4 B-panels (4MB) per XCD
  const long m0 = (long)(i_ >> 2) * 256;
  const int K = 2048;

  const int r0_ = tid >> 2;                       // rows 0..127 (load0), +128 (load1)
  const int kc0 = (tid & 3) ^ ((tid >> 3) & 3);   // slot ^ ((row>>1)&3)
  const __hip_bfloat16* sA0 = A + (m0 + r0_) * K + kc0 * 8;
  const __hip_bfloat16* sA1 = A + (m0 + r0_ + 128) * K + kc0 * 8;
  const __hip_bfloat16* sB0 = BT + (n0 + r0_) * K + kc0 * 8;
  const __hip_bfloat16* sB1 = BT + (n0 + r0_ + 128) * K + kc0 * 8;

  const int xq = (lo >> 1) & 3;
  const int aoff = (wm + lo) * 32 + ((quad ^ xq) * 8);
  const int boff = (wn + lo) * 32 + ((quad ^ xq) * 8);

  const f32x4 z4 = {0.f, 0.f, 0.f, 0.f};
  f32x4 acc[8][4];
#pragma unroll
  for (int fr = 0; fr < 8; ++fr)
#pragma unroll
    for (int fn = 0; fn < 4; ++fn) acc[fr][fn] = z4;

#define QG_STAGE(buf, kt) do {                                   \
    const int off_ = (kt) * 32;                                  \
    async16(sA0 + off_, &As[buf][tid * 8]);                      \
    async16(sA1 + off_, &As[buf][tid * 8 + 4096]);               \
    async16(sB0 + off_, &Bs[buf][tid * 8]);                      \
    async16(sB1 + off_, &Bs[buf][tid * 8 + 4096]);               \
  } while (0)

#define QG_COMPUTE(buf_) do {                                    \
    bf16x8 af[8], bq[4];                                         \
    _Pragma("unroll")                                            \
    for (int fr = 0; fr < 8; ++fr)                               \
      af[fr] = *(const bf16x8*)(&As[buf_][aoff + fr * 512]);     \
    _Pragma("unroll")                                            \
    for (int fn = 0; fn < 4; ++fn)                               \
      bq[fn] = *(const bf16x8*)(&Bs[buf_][boff + fn * 512]);     \
    __builtin_amdgcn_s_setprio(1);                               \
    _Pragma("unroll")                                            \
    for (int fr = 0; fr < 8; ++fr)                               \
      _Pragma("unroll")                                          \
      for (int fn = 0; fn < 4; ++fn)                             \
        acc[fr][fn] = MFMA16(af[fr], bq[fn], acc[fr][fn]);       \
    __builtin_amdgcn_s_setprio(0);                               \
  } while (0)

  QG_STAGE(0, 0); QG_STAGE(1, 1); QG_STAGE(2, 2);
  for (int kt = 0; kt < 61; ++kt) {
    asm volatile("s_waitcnt vmcnt(8)" ::: "memory");
    __builtin_amdgcn_s_barrier();
    __builtin_amdgcn_sched_barrier(0);
    QG_STAGE((kt + 3) & 3, kt + 3);
    __builtin_amdgcn_sched_barrier(0);
    QG_COMPUTE(kt & 3);
  }
  asm volatile("s_waitcnt vmcnt(8)" ::: "memory");
  __builtin_amdgcn_s_barrier();
  __builtin_amdgcn_sched_barrier(0);
  QG_COMPUTE(1);   // kt=61
  asm volatile("s_waitcnt vmcnt(4)" ::: "memory");
  __builtin_amdgcn_s_barrier();
  __builtin_amdgcn_sched_barrier(0);
  QG_COMPUTE(2);   // kt=62
  asm volatile("s_waitcnt vmcnt(0)" ::: "memory");
  __builtin_amdgcn_s_barrier();
  __builtin_amdgcn_sched_barrier(0);
  QG_COMPUTE(3);   // kt=63
#undef QG_STAGE
#undef QG_COMPUTE

#pragma unroll
  for (int fr = 0; fr < 8; ++fr)
#pragma unroll
    for (int fn = 0; fn < 4; ++fn)
#pragma unroll
      for (int rr = 0; rr < 4; ++rr) {
        long row = m0 + wm + fr * 16 + quad * 4 + rr;  // token t
        long col = n0 + wn + fn * 16 + lo;             // n in [0,8192)
        int head = (int)(col >> 9), c = (int)(col & 511);
        float v = acc[fr][fn][rr];
        if (c < 256)
          qout[(row * NH_SZ + head) * 256 + c] = v;
        else
          gate[(row * NH_SZ + head) * 256 + (c - 256)] = __float2bfloat16(v);
      }
}

// ---------------- out GEMM, deep-pipelined, BK=64 (round-7 amortization fix):
// A = packed hi/lo o-buffer viewed as interleaved bf16 (4096, 8192), async16'd
// directly (no repack). B = K-duplicated WoT image (2048, 8192) bf16.
// BM=256, BN=128, BK=64 as TWO 32-col sub-tiles each in gemm_qg2's exact LDS
// layout+swizzle. 3-deep ring (144KB LDS), vmcnt(6), 1 barrier/K-tile,
// 32 MFMA/wave/barrier, 128 K-tiles. XCD grouping: 2 n-panels (4MB) per XCD.
__global__ __launch_bounds__(512) void gemm_out2(const __hip_bfloat16* __restrict__ A,
                                                 const __hip_bfloat16* __restrict__ BT,
                                                 float* __restrict__ C) {
  __shared__ __align__(16) __hip_bfloat16 As[3][2][8192];  // [buf][ks][row 256][32]
  __shared__ __align__(16) __hip_bfloat16 Bs[3][2][4096];  // [buf][ks][row 128][32]
  const int tid = threadIdx.x, wid = tid >> 6, lane = tid & 63;
  const int lo = lane & 15, quad = lane >> 4;
  const int wm = (wid >> 1) * 64, wn = (wid & 1) * 64;   // 4m x 2n waves
  const int wg = blockIdx.x + blockIdx.y * 8;            // 256 wgs
  const int xcd = wg & 7, i_ = wg >> 3;                  // i_ in [0,32)
  const long n0 = (long)(xcd * 2 + (i_ & 1)) * 128;      // 2 B-panels (4MB) per XCD
  const long m0 = (long)(i_ >> 1) * 256;
  const long Kp = 8192;

  // staging (per 32-col sub-tile, identical to qg2): row=tid>>2, swizzled slot
  const int r0_ = tid >> 2;
  const int kc0 = (tid & 3) ^ ((tid >> 3) & 3);
  const __hip_bfloat16* sA0 = A + (m0 + r0_) * Kp + kc0 * 8;
  const __hip_bfloat16* sA1 = A + (m0 + r0_ + 128) * Kp + kc0 * 8;
  const __hip_bfloat16* sB0 = BT + (n0 + r0_) * Kp + kc0 * 8;   // rows 0..127

  // read side: same XOR as qg2
  const int xq = (lo >> 1) & 3;
  const int aoff = (wm + lo) * 32 + ((quad ^ xq) * 8);
  const int boff = (wn + lo) * 32 + ((quad ^ xq) * 8);

  const f32x4 z4 = {0.f, 0.f, 0.f, 0.f};
  f32x4 acc[4][4];
#pragma unroll
  for (int fr = 0; fr < 4; ++fr)
#pragma unroll
    for (int fn = 0; fn < 4; ++fn) acc[fr][fn] = z4;

#define GO_STAGE(buf, kt) do {                                   \
    const long off_ = (long)(kt) * 64;                           \
    async16(sA0 + off_,      &As[buf][0][tid * 8]);              \
    async16(sA1 + off_,      &As[buf][0][tid * 8 + 4096]);       \
    async16(sA0 + off_ + 32, &As[buf][1][tid * 8]);              \
    async16(sA1 + off_ + 32, &As[buf][1][tid * 8 + 4096]);       \
    async16(sB0 + off_,      &Bs[buf][0][tid * 8]);              \
    async16(sB0 + off_ + 32, &Bs[buf][1][tid * 8]);              \
  } while (0)

#define GO_COMPUTE(buf_) do {                                    \
    _Pragma("unroll")                                            \
    for (int ks = 0; ks < 2; ++ks) {                             \
      bf16x8 af[4], bq[4];                                       \
      _Pragma("unroll")                                          \
      for (int fr = 0; fr < 4; ++fr)                             \
        af[fr] = *(const bf16x8*)(&As[buf_][ks][aoff + fr * 512]); \
      _Pragma("unroll")                                          \
      for (int fn = 0; fn < 4; ++fn)                             \
        bq[fn] = *(const bf16x8*)(&Bs[buf_][ks][boff + fn * 512]); \
      __builtin_amdgcn_s_setprio(1);                             \
      _Pragma("unroll")                                          \
      for (int fr = 0; fr < 4; ++fr)                             \
        _Pragma("unroll")                                        \
        for (int fn = 0; fn < 4; ++fn)                           \
          acc[fr][fn] = MFMA16(af[fr], bq[fn], acc[fr][fn]);     \
      __builtin_amdgcn_s_setprio(0);                             \
    }                                                            \
  } while (0)

  // 128 K-tiles of 64; 6-op stages; 2 tiles in flight -> wait to 6
  GO_STAGE(0, 0); GO_STAGE(1, 1);
  for (int kt = 0; kt < 126; ++kt) {
    asm volatile("s_waitcnt vmcnt(6)" ::: "memory");
    __builtin_amdgcn_s_barrier();
    __builtin_amdgcn_sched_barrier(0);
    GO_STAGE((kt + 2) % 3, kt + 2);
    __builtin_amdgcn_sched_barrier(0);
    GO_COMPUTE(kt % 3);
  }
  asm volatile("s_waitcnt vmcnt(6)" ::: "memory");
  __builtin_amdgcn_s_barrier();
  __builtin_amdgcn_sched_barrier(0);
  GO_COMPUTE(0);   // kt=126 (126%3==0)
  asm volatile("s_waitcnt vmcnt(0)" ::: "memory");
  __builtin_amdgcn_s_barrier();
  __builtin_amdgcn_sched_barrier(0);
  GO_COMPUTE(1);   // kt=127 (127%3==1)
#undef GO_STAGE
#undef GO_COMPUTE

#pragma unroll
  for (int fr = 0; fr < 4; ++fr)
#pragma unroll
    for (int fn = 0; fn < 4; ++fn)
#pragma unroll
      for (int rr = 0; rr < 4; ++rr) {
        long row = m0 + wm + fr * 16 + quad * 4 + rr;
        long col = n0 + wn + fn * 16 + lo;
        C[row * 2048 + col] = acc[fr][fn][rr];
      }
}

// --------------------------- fused K+V projection GEMM (N=1024; WkT||WvT rows)
__global__ __launch_bounds__(256) void gemm_kv(const __hip_bfloat16* __restrict__ A,
                                               const __hip_bfloat16* __restrict__ BT,
                                               float* __restrict__ kf,
                                               __hip_bfloat16* __restrict__ vraw,
                                               int M, int N, int K) {
  __shared__ __align__(16) __hip_bfloat16 As[128 * 32];
  __shared__ __align__(16) __hip_bfloat16 Bs[128 * 32];
  const int tid = threadIdx.x;
  const int wid = tid >> 6, lane = tid & 63;
  const int lo = lane & 15, quad = lane >> 4;
  const int wq = blockIdx.x + blockIdx.y * 8;    // nwg = 256
  const int xcd = wq & 7, idx = wq >> 3;         // idx in [0,32)
  const long n0 = (long)xcd * 128;
  const long m0 = (long)idx * 128;
  const int wm = (wid >> 1) * 64, wn = (wid & 1) * 64;
  const f32x4 z4 = {0.f, 0.f, 0.f, 0.f};
  f32x4 acc[4][4];
#pragma unroll
  for (int i = 0; i < 4; ++i)
#pragma unroll
    for (int j = 0; j < 4; ++j) acc[i][j] = z4;

  const int cf0 = tid, cf1 = 256 + tid;
  const int r0_ = cf0 >> 2, c0_ = (cf0 & 3) * 8;
  const int r1_ = cf1 >> 2, c1_ = (cf1 & 3) * 8;
  const __hip_bfloat16* a0 = A + (m0 + r0_) * K + c0_;
  const __hip_bfloat16* a1 = A + (m0 + r1_) * K + c1_;
  const __hip_bfloat16* b0 = BT + (n0 + r0_) * K + c0_;
  const __hip_bfloat16* b1 = BT + (n0 + r1_) * K + c1_;

  for (int k0 = 0; k0 < K; k0 += 32) {
    async16(a0 + k0, As + cf0 * 8);
    async16(a1 + k0, As + cf1 * 8);
    async16(b0 + k0, Bs + cf0 * 8);
    async16(b1 + k0, Bs + cf1 * 8);
    __syncthreads();
    bf16x8 af[4], bfv[4];
#pragma unroll
    for (int i = 0; i < 4; ++i)
      af[i] = *(const bf16x8*)(As + (wm + i * 16 + lo) * 32 + quad * 8);
#pragma unroll
    for (int i = 0; i < 4; ++i)
      bfv[i] = *(const bf16x8*)(Bs + (wn + i * 16 + lo) * 32 + quad * 8);
#pragma unroll
    for (int i = 0; i < 4; ++i)
#pragma unroll
      for (int j = 0; j < 4; ++j) acc[i][j] = MFMA16(af[i], bfv[j], acc[i][j]);
    __syncthreads();
  }
#pragma unroll
  for (int i = 0; i < 4; ++i)
#pragma unroll
    for (int j = 0; j < 4; ++j)
#pragma unroll
      for (int r = 0; r < 4; ++r) {
        long row = m0 + wm + i * 16 + quad * 4 + r;
        long col = n0 + wn + j * 16 + lo;          // [0,1024)
        float v = acc[i][j][r];
        if (col < 512)
          kf[row * 512 + col] = v;
        else
          vraw[row * 512 + (col - 512)] = __float2bfloat16(v);
      }
}

// --------------------------------------- V -> swizzled LDS-image layout
__global__ __launch_bounds__(256) void v_swizzle(const __hip_bfloat16* __restrict__ vraw,
                                                 __hip_bfloat16* __restrict__ vsw) {
  const int ktt = blockIdx.x, kvh = blockIdx.y, tid = threadIdx.x;
  __shared__ __hip_bfloat16 L[64 * 264];
#pragma unroll
  for (int it = 0; it < 8; ++it) {
    int cf = it * 256 + tid;           // 2048 chunks of 8 elems
    int kv = cf >> 5, d0 = (cf & 31) * 8;
    *(uint4*)&L[kv * 264 + d0] =
        *(const uint4*)&vraw[(((long)ktt * 64 + kv) * NKV_SZ + kvh) * 256 + d0];
  }
  __syncthreads();
#pragma unroll
  for (int it = 0; it < 8; ++it) {
    int cf = it * 256 + tid;           // c in [0,8), d in [0,256)
    int c = cf >> 8, d = cf & 255;
    union { __hip_bfloat16 h[8]; uint4 u; } t;
#pragma unroll
    for (int e = 0; e < 8; ++e) t.h[e] = L[(c * 8 + e) * 264 + d];
    *(uint4*)&vsw[((long)kvh * 64 + ktt) * 16384 + (long)(c * 256 + d) * 8] = t.u;
  }
}

// ---- RMSNorm + RoPE, wave-per-row (no LDS, no barriers). 4 rows per block.
__global__ __launch_bounds__(256) void norm_rope_wave(float* __restrict__ qbuf,
                                                      const float* __restrict__ kbuf,
                                                      __hip_bfloat16* __restrict__ ksw,
                                                      const int* __restrict__ pos,
                                                      const float* __restrict__ qw,
                                                      const float* __restrict__ kw) {
  const int id = blockIdx.x * 4 + (threadIdx.x >> 6);   // row id in [0, 4096*18)
  const int lane = threadIdx.x & 63;
  const int h = id % 18, t = id / 18;
  const bool isq = h < NH_SZ;
  const float* ptr = isq ? qbuf + ((long)t * NH_SZ + h) * 256
                         : kbuf + ((long)t * NKV_SZ + (h - NH_SZ)) * 256;
  const float* w = isq ? qw : kw;
  float4 v = *(const float4*)(ptr + lane * 4);   // d = lane*4 + j
  float4 wv = *(const float4*)(w + lane * 4);
  float s2 = v.x * v.x + v.y * v.y + v.z * v.z + v.w * v.w;
#pragma unroll
  for (int o = 32; o > 0; o >>= 1) s2 += __shfl_xor(s2, o);
  float sc = rsqrtf(s2 * (1.0f / 256.0f) + EPS_);
  float n[4];
  n[0] = v.x * sc * (1.0f + wv.x);
  n[1] = v.y * sc * (1.0f + wv.y);
  n[2] = v.z * sc * (1.0f + wv.z);
  n[3] = v.w * sc * (1.0f + wv.w);
  float pr[4];
#pragma unroll
  for (int j = 0; j < 4; ++j) pr[j] = __shfl_xor(n[j], 8);
  float o4[4];
  if (lane < 16) {
    int base_i = (lane & 7) * 4;
#pragma unroll
    for (int j = 0; j < 4; ++j) {
      int i = base_i + j;
      float p = (float)pos[(i % 3) * T_SZ + t];
      float fr = p * exp2f((float)i * (-0.72667177075661f));  // 1e7^(-i/32)
      float c, s;
      sincosf(fr, &s, &c);
      o4[j] = (lane < 8) ? n[j] * c - pr[j] * s : n[j] * c + pr[j] * s;
    }
  } else {
#pragma unroll
    for (int j = 0; j < 4; ++j) o4[j] = n[j];
  }
  if (isq) {
    uint4 u;
    u.x = pack_hilo(o4[0]); u.y = pack_hilo(o4[1]);
    u.z = pack_hilo(o4[2]); u.w = pack_hilo(o4[3]);
    *(uint4*)((unsigned*)qbuf + ((long)t * NH_SZ + h) * 256 + lane * 4) = u;
  } else {
    int kv = h - NH_SZ;
    long tt = t >> 5; int r = t & 31;
    int c = lane >> 1, e0 = (lane & 1) * 4;
    union { __hip_bfloat16 h4[4]; uint2 u; } kk;
#pragma unroll
    for (int j = 0; j < 4; ++j) kk.h4[j] = __float2bfloat16(o4[j]);
    *(uint2*)&ksw[(((long)kv * 128 + tt) * 32 + c) * 256 + r * 8 + e0] = kk.u;
  }
}

// ------------------------------------------------------- flash causal attention
__global__ __launch_bounds__(256) void attn_kernel(unsigned* __restrict__ Qp,
                                                   const __hip_bfloat16* __restrict__ Ksw,
                                                   const __hip_bfloat16* __restrict__ Vsw,
                                                   const __hip_bfloat16* __restrict__ Gt) {
  const int w = blockIdx.x + blockIdx.y * 64;
  const int xcd = w & 7, j = w >> 3;           // j in [0,128)
  const int h = xcd * 2 + (j & 1);
  const int qt = 63 - (j >> 1);
  const int kvh = h >> 3;
  const int tid = threadIdx.x, wid = tid >> 6, lane = tid & 63;
  const int lo = lane & 15, quad = lane >> 4;
  __shared__ __align__(16) __hip_bfloat16 Ks[32 * 256];   // [c=d/8][r=kv%32][e]
  __shared__ __align__(16) __hip_bfloat16 Vs[4 * 2048];   // [cc=kv/8][d=256][e]
  __shared__ __align__(16) __hip_bfloat16 Ps[4][16 * 40]; // per-wave 16x32, stride 40

  __hip_bfloat16* myP = &Ps[wid][0];
  const f32x4 z4 = {0.f, 0.f, 0.f, 0.f};
  const int nt = 2 * (qt + 1);                 // 32-row KV tiles

  bf16x8 qh[8], ql[8];
  {
    const unsigned* qp =
        Qp + ((long)(qt * 64 + wid * 16 + lo) * NH_SZ + h) * 256 + quad * 8;
#pragma unroll
    for (int kc = 0; kc < 8; ++kc) {
      uint4 p0 = *(const uint4*)(qp + kc * 32);
      uint4 p1 = *(const uint4*)(qp + kc * 32 + 4);
      bf16x8 a, b;
      a[0] = (short)(p0.x & 0xffff); b[0] = (short)(p0.x >> 16);
      a[1] = (short)(p0.y & 0xffff); b[1] = (short)(p0.y >> 16);
      a[2] = (short)(p0.z & 0xffff); b[2] = (short)(p0.z >> 16);
      a[3] = (short)(p0.w & 0xffff); b[3] = (short)(p0.w >> 16);
      a[4] = (short)(p1.x & 0xffff); b[4] = (short)(p1.x >> 16);
      a[5] = (short)(p1.y & 0xffff); b[5] = (short)(p1.y >> 16);
      a[6] = (short)(p1.z & 0xffff); b[6] = (short)(p1.z >> 16);
      a[7] = (short)(p1.w & 0xffff); b[7] = (short)(p1.w >> 16);
      qh[kc] = a; ql[kc] = b;
    }
  }

  f32x4 acc[16];
#pragma unroll
  for (int od = 0; od < 16; ++od) acc[od] = z4;
  float lsum[4];
#pragma unroll
  for (int r = 0; r < 4; ++r) lsum[r] = 0.f;

  const int qrow_g = qt * 64 + wid * 16 + quad * 4;
  const __hip_bfloat16* kbase = Ksw + (long)kvh * 1048576;  // 128 tiles * 8192
  const __hip_bfloat16* vbase = Vsw + (long)kvh * 1048576;

#pragma unroll
  for (int i = 0; i < 4; ++i) {
    int m = i * 4 + wid;
    async16(kbase + m * 512 + lane * 8, Ks + m * 512 + lane * 8);
    async16(vbase + m * 512 + lane * 8, Vs + m * 512 + lane * 8);
  }
  __syncthreads();  // drain K(0), V(0)

  for (int kt = 0; kt < nt; ++kt) {
    const bool skip = (kt == nt - 1) && (wid < 2);
    f32x4 s[2];
    s[0] = z4; s[1] = z4;
    if (!skip) {
      __builtin_amdgcn_s_setprio(1);
#pragma unroll
      for (int kc = 0; kc < 8; ++kc) {
        bf16x8 ah = qh[kc], al = ql[kc];
#pragma unroll
        for (int ni = 0; ni < 2; ++ni) {
          bf16x8 b = *(const bf16x8*)(Ks + (kc * 4 + quad) * 256 + (ni * 16 + lo) * 8);
          s[ni] = MFMA16(ah, b, s[ni]);
          s[ni] = MFMA16(al, b, s[ni]);
        }
      }
      __builtin_amdgcn_s_setprio(0);
    }
    __syncthreads();  // B: Ks(kt) reads done; drains V(kt) prefetch
    if (kt + 1 < nt) {
      const __hip_bfloat16* kb = kbase + (long)(kt + 1) * 8192;
#pragma unroll
      for (int i = 0; i < 4; ++i) {
        int m = i * 4 + wid;
        async16(kb + m * 512 + lane * 8, Ks + m * 512 + lane * 8);
      }
    }
    if (!skip) {
      float sv[2][4];
      if (kt >= nt - 2) {
#pragma unroll
        for (int ni = 0; ni < 2; ++ni) {
          int kcol = kt * 32 + ni * 16 + lo;
#pragma unroll
          for (int r = 0; r < 4; ++r) {
            float e = __expf(fmaf(s[ni][r], ATT_SCALE, -SOFT_M));
            sv[ni][r] = (kcol > qrow_g + r) ? 0.f : e;
          }
        }
      } else {
#pragma unroll
        for (int ni = 0; ni < 2; ++ni)
#pragma unroll
          for (int r = 0; r < 4; ++r)
            sv[ni][r] = __expf(fmaf(s[ni][r], ATT_SCALE, -SOFT_M));
      }
#pragma unroll
      for (int r = 0; r < 4; ++r) lsum[r] += sv[0][r] + sv[1][r];
#pragma unroll
      for (int ni = 0; ni < 2; ++ni)
#pragma unroll
        for (int r = 0; r < 4; ++r)
          myP[(quad * 4 + r) * 40 + ni * 16 + lo] = __float2bfloat16(sv[ni][r]);
      bf16x8 ap = *(const bf16x8*)(myP + lo * 40 + quad * 8);
      __builtin_amdgcn_s_setprio(1);
#pragma unroll
      for (int od = 0; od < 16; ++od) {
        bf16x8 bv = *(const bf16x8*)(Vs + quad * 2048 + (od * 16 + lo) * 8);
        acc[od] = MFMA16(ap, bv, acc[od]);
      }
      __builtin_amdgcn_s_setprio(0);
    }
    __syncthreads();  // C: Vs(kt) reads done; drains K(kt+1) prefetch
    if (kt + 1 < nt) {
      const __hip_bfloat16* vb = vbase + (long)(kt + 1) * 8192;
#pragma unroll
      for (int i = 0; i < 4; ++i) {
        int m = i * 4 + wid;
        async16(vb + m * 512 + lane * 8, Vs + m * 512 + lane * 8);
      }
    }
  }

  float l_r[4];
#pragma unroll
  for (int r = 0; r < 4; ++r) {
    float su = lsum[r];
#pragma unroll
    for (int off = 1; off < 16; off <<= 1) su += __shfl_xor(su, off);
    l_r[r] = su;
  }
#pragma unroll
  for (int od = 0; od < 16; ++od)
#pragma unroll
    for (int r = 0; r < 4; ++r) {
      int trow = qt * 64 + wid * 16 + quad * 4 + r;
      int col = od * 16 + lo;
      long idx = ((long)trow * NH_SZ + h) * 256 + col;
      float g = __bfloat162float(Gt[idx]);
      float sig = 1.0f / (1.0f + expf(-g));
      float v = (acc[od][r] / l_r[r]) * sig;
      Qp[idx] = pack_hilo(v);
    }
}

// ------------------------------------------------------------------- launcher
extern "C" void kernel_launch(void* const* d_in, const int* in_sizes, int n_in,
                              void* d_out, int out_size, void* d_ws, size_t ws_size,
                              hipStream_t stream) {
  (void)in_sizes; (void)n_in; (void)out_size; (void)ws_size;
  const int* positions = (const int*)d_in[0];
  const float* hidden = (const float*)d_in[1];
  const float* Wq = (const float*)d_in[2];
  const float* Wk = (const float*)d_in[3];
  const float* Wv = (const float*)d_in[4];
  const float* Wo = (const float*)d_in[5];
  const float* qw = (const float*)d_in[6];
  const float* kw = (const float*)d_in[7];
  float* out = (float*)d_out;
  char* ws = (char*)d_ws;

  // layout (bytes), total exactly 160 MiB:
  __hip_bfloat16* hid  = (__hip_bfloat16*)(ws + 0);           // 16 MB (dead after GEMMs)
  __hip_bfloat16* WqT  = (__hip_bfloat16*)(ws + 16777216);    // 32 MB (dead after gemm_qg2)
  __hip_bfloat16* WkT  = (__hip_bfloat16*)(ws + 50331648);    //  2 MB  (WvT contiguous after)
  __hip_bfloat16* WvT  = (__hip_bfloat16*)(ws + 52428800);    //  2 MB
  float*          qf   = (float*)(ws + 54525952);             // 64 MB fp32 q -> packed -> o packed
  __hip_bfloat16* gate = (__hip_bfloat16*)(ws + 121634816);   // 32 MB (T,16,256)
  float*          kf   = (float*)(ws + 155189248);            //  8 MB (T,2,256) fp32
  __hip_bfloat16* vraw = (__hip_bfloat16*)(ws + 163577856);   //  4 MB -> end 167,772,160
  __hip_bfloat16* Ksw  = WkT;                                  // alias 4 MB [WkT+WvT] after kv GEMM
  __hip_bfloat16* Vsw  = hid;                                  // alias 4 MB of hid after GEMMs
  unsigned*       Wo2  = (unsigned*)WqT;                       // alias 32 MB: K-dup WoT image
  unsigned* qpk = (unsigned*)qf;

  // 1) casts / transposes
  cast_f32_bf16<<<dim3(8192), dim3(256), 0, stream>>>(hidden, hid, 2097152);
  transpose_cast<float><<<dim3(256, 64), dim3(256), 0, stream>>>(Wq, WqT, 2048, 8192);
  transpose_cast<float><<<dim3(16, 64), dim3(256), 0, stream>>>(Wk, WkT, 2048, 512);
  transpose_cast<float><<<dim3(16, 64), dim3(256), 0, stream>>>(Wv, WvT, 2048, 512);
  // 2) projections: q fp32 + gate bf16 (deep-pipelined 256^2); fused k/v
  gemm_qg2<<<dim3(8, 64), dim3(512), 0, stream>>>(hid, WqT, qf, gate);
  gemm_kv<<<dim3(8, 32), dim3(256), 0, stream>>>(hid, WkT, kf, vraw, 4096, 1024, 2048);
  // 3) V -> swizzled (after GEMMs: Vsw aliases hid)
  v_swizzle<<<dim3(64, 2), dim3(256), 0, stream>>>(vraw, Vsw);
  // 4) RMSNorm + RoPE, wave-per-row: q packed in-place; k swizzled -> Ksw
  norm_rope_wave<<<dim3(18432), dim3(256), 0, stream>>>(qf, kf, Ksw, positions, qw, kw);
  // 5) flash attention, one q-tile per block, big-first + XCD swizzle
  attn_kernel<<<dim3(64, 16), dim3(256), 0, stream>>>(qpk, Ksw, Vsw, gate);
  // 6) Wo -> K-dup bf16 image (into dead WqT), then deep-pipelined BK=64 out
  //    GEMM: packed o-buffer read directly as interleaved bf16 (no repack).
  transpose_dup<<<dim3(64, 128), dim3(256), 0, stream>>>(Wo, Wo2, 4096, 2048);
  gemm_out2<<<dim3(8, 32), dim3(512), 0, stream>>>((const __hip_bfloat16*)qpk,
                                                   (const __hip_bfloat16*)Wo2, out);
}

// Round 8
// 826.288 us; speedup vs baseline: 1.0431x; 1.0023x over previous
//
#include <hip/hip_runtime.h>
#include <hip/hip_bf16.h>

// Qwen3.5 attention block: T=4096, H=2048, NH=16, NKV=2, HD=256, ROT=64
// bf16 MFMA (16x16x32) with fp32 accumulate; precision-critical intermediates
// kept fp32 or split into bf16 hi/lo pairs (packed ushort2 in 4B slots).
// Attn: KV tile = 32 rows, LDS 37888B -> 3 blocks/CU, rotated prefetch.
// gemm_qg2: deep-pipeline 4-deep LDS ring, counted vmcnt, 1 barrier/K-tile,
// XOR-swizzled staging, XCD n-panel grouping, and FUSED q-RMSNorm+RoPE+pack
// epilogue (q blocks hold complete 256-dim q vectors; RoPE pairs are same-lane
// register pairs fn<->fn+2). Output GEMM: proven 2-barrier hi/lo 2-pass
// (deep-pipeline variants were A/B-tested slower in rounds 6-7).

#define T_SZ 4096
#define H_SZ 2048
#define NH_SZ 16
#define NKV_SZ 2
#define HD_SZ 256
#define ATT_SCALE 0.0625f   // HD^-0.5
#define SOFT_M 18.0f        // fixed softmax shift
#define EPS_ 1e-6f

typedef __attribute__((ext_vector_type(8))) short bf16x8;   // 8 bf16 = 4 VGPRs
typedef __attribute__((ext_vector_type(4))) float f32x4;

#define MFMA16(a, b, c) __builtin_amdgcn_mfma_f32_16x16x32_bf16((a), (b), (c), 0, 0, 0)

__device__ __forceinline__ void async16(const void* g, void* l) {
  __builtin_amdgcn_global_load_lds((const __attribute__((address_space(1))) void*)g,
                                   (__attribute__((address_space(3))) void*)l,
                                   16, 0, 0);
}

__device__ __forceinline__ float to_f(float x) { return x; }
__device__ __forceinline__ float to_f(__hip_bfloat16 x) { return __bfloat162float(x); }

union BfBits { __hip_bfloat16 h; unsigned short u; };

__device__ __forceinline__ unsigned short bf16_bits(__hip_bfloat16 h) {
  BfBits t; t.h = h; return t.u;
}

__device__ __forceinline__ unsigned pack_hilo(float v) {
  __hip_bfloat16 hi = __float2bfloat16(v);
  float rem = v - __bfloat162float(hi);
  __hip_bfloat16 lo = __float2bfloat16(rem);
  return (unsigned)bf16_bits(hi) | ((unsigned)bf16_bits(lo) << 16);
}

// ---------------------------------------------------------------- cast hidden
__global__ __launch_bounds__(256) void cast_f32_bf16(const float* __restrict__ in,
                                                     __hip_bfloat16* __restrict__ out,
                                                     int n4) {
  int i = blockIdx.x * 256 + threadIdx.x;
  if (i >= n4) return;
  float4 v = ((const float4*)in)[i];
  union { __hip_bfloat16 h[4]; uint2 u; } t;
  t.h[0] = __float2bfloat16(v.x);
  t.h[1] = __float2bfloat16(v.y);
  t.h[2] = __float2bfloat16(v.z);
  t.h[3] = __float2bfloat16(v.w);
  ((uint2*)out)[i] = t.u;
}

// ------------------------------------------------------- transpose (+cast bf16)
template <typename TIN>
__global__ __launch_bounds__(256) void transpose_cast(const TIN* __restrict__ in,
                                                      __hip_bfloat16* __restrict__ out,
                                                      int R, int C) {
  __shared__ TIN tile[32][33];
  int c0 = blockIdx.x * 32, r0 = blockIdx.y * 32;
  int tx = threadIdx.x & 31, ty = threadIdx.x >> 5;
#pragma unroll
  for (int i = 0; i < 32; i += 8)
    tile[ty + i][tx] = in[(long)(r0 + ty + i) * C + c0 + tx];
  __syncthreads();
#pragma unroll
  for (int i = 0; i < 32; i += 8)
    out[(long)(c0 + ty + i) * R + r0 + tx] = __float2bfloat16(to_f(tile[tx][ty + i]));
}

// ---------------- Wq GEMM, deep-pipelined, with FUSED q-norm/RoPE/pack epilogue
// 256x256 tile, BK=32, 4-deep LDS ring, counted vmcnt, quad-XOR LDS swizzle.
// q blocks ((n0>>8)&1==0): cols n0..n0+255 == the full 256-dim q vector of head
// n0>>9 for 256 tokens -> RMSNorm via per-wave shfl + 4KB LDS cross-wave reduce
// (reusing As), RoPE in-register (pairs fn<->fn+2, wn==0 waves only), pack_hilo
// store. Gate blocks: plain bf16 store.
__global__ __launch_bounds__(512) void gemm_qg2(const __hip_bfloat16* __restrict__ A,
                                                const __hip_bfloat16* __restrict__ BT,
                                                unsigned* __restrict__ qpk,
                                                __hip_bfloat16* __restrict__ gate,
                                                const int* __restrict__ pos,
                                                const float* __restrict__ qw) {
  __shared__ __align__(16) __hip_bfloat16 As[4][8192];  // [buf][kcslot 4][row 256][e 8]
  __shared__ __align__(16) __hip_bfloat16 Bs[4][8192];
  const int tid = threadIdx.x, wid = tid >> 6, lane = tid & 63;
  const int lo = lane & 15, quad = lane >> 4;
  const int wm = (wid >> 2) * 128, wn = (wid & 3) * 64;  // 2m x 4n waves
  const int wnx = wid & 3;
  const int wg = blockIdx.x + blockIdx.y * 8;            // 512 wgs
  const int xcd = wg & 7, i_ = wg >> 3;                  // i_ in [0,64)
  const long n0 = (long)(xcd * 4 + (i_ & 3)) * 256;      // 4 B-panels (4MB) per XCD
  const long m0 = (long)(i_ >> 2) * 256;
  const int K = 2048;

  const int r0_ = tid >> 2;                       // rows 0..127 (load0), +128 (load1)
  const int kc0 = (tid & 3) ^ ((tid >> 3) & 3);   // slot ^ ((row>>1)&3)
  const __hip_bfloat16* sA0 = A + (m0 + r0_) * K + kc0 * 8;
  const __hip_bfloat16* sA1 = A + (m0 + r0_ + 128) * K + kc0 * 8;
  const __hip_bfloat16* sB0 = BT + (n0 + r0_) * K + kc0 * 8;
  const __hip_bfloat16* sB1 = BT + (n0 + r0_ + 128) * K + kc0 * 8;

  const int xq = (lo >> 1) & 3;
  const int aoff = (wm + lo) * 32 + ((quad ^ xq) * 8);
  const int boff = (wn + lo) * 32 + ((quad ^ xq) * 8);

  const f32x4 z4 = {0.f, 0.f, 0.f, 0.f};
  f32x4 acc[8][4];
#pragma unroll
  for (int fr = 0; fr < 8; ++fr)
#pragma unroll
    for (int fn = 0; fn < 4; ++fn) acc[fr][fn] = z4;

#define QG_STAGE(buf, kt) do {                                   \
    const int off_ = (kt) * 32;                                  \
    async16(sA0 + off_, &As[buf][tid * 8]);                      \
    async16(sA1 + off_, &As[buf][tid * 8 + 4096]);               \
    async16(sB0 + off_, &Bs[buf][tid * 8]);                      \
    async16(sB1 + off_, &Bs[buf][tid * 8 + 4096]);               \
  } while (0)

#define QG_COMPUTE(buf_) do {                                    \
    bf16x8 af[8], bq[4];                                         \
    _Pragma("unroll")                                            \
    for (int fr = 0; fr < 8; ++fr)                               \
      af[fr] = *(const bf16x8*)(&As[buf_][aoff + fr * 512]);     \
    _Pragma("unroll")                                            \
    for (int fn = 0; fn < 4; ++fn)                               \
      bq[fn] = *(const bf16x8*)(&Bs[buf_][boff + fn * 512]);     \
    __builtin_amdgcn_s_setprio(1);                               \
    _Pragma("unroll")                                            \
    for (int fr = 0; fr < 8; ++fr)                               \
      _Pragma("unroll")                                          \
      for (int fn = 0; fn < 4; ++fn)                             \
        acc[fr][fn] = MFMA16(af[fr], bq[fn], acc[fr][fn]);       \
    __builtin_amdgcn_s_setprio(0);                               \
  } while (0)

  QG_STAGE(0, 0); QG_STAGE(1, 1); QG_STAGE(2, 2);
  for (int kt = 0; kt < 61; ++kt) {
    asm volatile("s_waitcnt vmcnt(8)" ::: "memory");
    __builtin_amdgcn_s_barrier();
    __builtin_amdgcn_sched_barrier(0);
    QG_STAGE((kt + 3) & 3, kt + 3);
    __builtin_amdgcn_sched_barrier(0);
    QG_COMPUTE(kt & 3);
  }
  asm volatile("s_waitcnt vmcnt(8)" ::: "memory");
  __builtin_amdgcn_s_barrier();
  __builtin_amdgcn_sched_barrier(0);
  QG_COMPUTE(1);   // kt=61
  asm volatile("s_waitcnt vmcnt(4)" ::: "memory");
  __builtin_amdgcn_s_barrier();
  __builtin_amdgcn_sched_barrier(0);
  QG_COMPUTE(2);   // kt=62
  asm volatile("s_waitcnt vmcnt(0)" ::: "memory");
  __builtin_amdgcn_s_barrier();
  __builtin_amdgcn_sched_barrier(0);
  QG_COMPUTE(3);   // kt=63
#undef QG_STAGE
#undef QG_COMPUTE

  const int head = (int)(n0 >> 9);
  const bool isq = ((n0 >> 8) & 1) == 0;
  if (!isq) {
    // ---- gate half: plain bf16 store (c-256 = wn + fn*16 + lo)
#pragma unroll
    for (int fr = 0; fr < 8; ++fr)
#pragma unroll
      for (int fn = 0; fn < 4; ++fn)
#pragma unroll
        for (int rr = 0; rr < 4; ++rr) {
          long row = m0 + wm + fr * 16 + quad * 4 + rr;
          int c = wn + fn * 16 + lo;
          gate[(row * NH_SZ + head) * 256 + c] = __float2bfloat16(acc[fr][fn][rr]);
        }
  } else {
    // ---- q half: fused RMSNorm + RoPE + hi/lo pack
    __syncthreads();                       // all frag reads done; reuse As as scratch
    float* red = (float*)&As[0][0];        // [256 rows][4 wn] floats = 4KB
#pragma unroll
    for (int fr = 0; fr < 8; ++fr)
#pragma unroll
      for (int rr = 0; rr < 4; ++rr) {
        float p = 0.f;
#pragma unroll
        for (int fn = 0; fn < 4; ++fn) { float x = acc[fr][fn][rr]; p += x * x; }
#pragma unroll
        for (int off = 1; off < 16; off <<= 1) p += __shfl_xor(p, off);
        if (lo == 0) red[(wm + fr * 16 + quad * 4 + rr) * 4 + wnx] = p;
      }
    __syncthreads();
    float wq4[4];
#pragma unroll
    for (int fn = 0; fn < 4; ++fn) wq4[fn] = 1.0f + qw[wn + fn * 16 + lo];
#pragma unroll
    for (int fr = 0; fr < 8; ++fr)
#pragma unroll
      for (int rr = 0; rr < 4; ++rr) {
        int rl = wm + fr * 16 + quad * 4 + rr;
        float4 rv = *(const float4*)&red[rl * 4];
        float sc = rsqrtf((rv.x + rv.y + rv.z + rv.w) * (1.0f / 256.0f) + EPS_);
        float v[4];
#pragma unroll
        for (int fn = 0; fn < 4; ++fn) v[fn] = acc[fr][fn][rr] * sc * wq4[fn];
        long row = m0 + rl;                // token t
        if (wnx == 0) {
          // RoPE on cols 0..63: pairs (d, d+32) == (fn, fn+2) same lane
#pragma unroll
          for (int fnp = 0; fnp < 2; ++fnp) {
            int i = fnp * 16 + lo;         // freq index 0..31
            float p = (float)pos[(i % 3) * T_SZ + row];
            float fr_ = p * exp2f((float)i * (-0.72667177075661f));  // 1e7^(-i/32)
            float cc, ss;
            sincosf(fr_, &ss, &cc);
            float x1 = v[fnp], x2 = v[fnp + 2];
            v[fnp] = x1 * cc - x2 * ss;
            v[fnp + 2] = x2 * cc + x1 * ss;
          }
        }
        long base = (row * NH_SZ + head) * 256;
#pragma unroll
        for (int fn = 0; fn < 4; ++fn)
          qpk[base + wn + fn * 16 + lo] = pack_hilo(v[fn]);
      }
  }
}

// --------------------------- fused K+V projection GEMM (N=1024; WkT||WvT rows)
__global__ __launch_bounds__(256) void gemm_kv(const __hip_bfloat16* __restrict__ A,
                                               const __hip_bfloat16* __restrict__ BT,
                                               float* __restrict__ kf,
                                               __hip_bfloat16* __restrict__ vraw,
                                               int M, int N, int K) {
  __shared__ __align__(16) __hip_bfloat16 As[128 * 32];
  __shared__ __align__(16) __hip_bfloat16 Bs[128 * 32];
  const int tid = threadIdx.x;
  const int wid = tid >> 6, lane = tid & 63;
  const int lo = lane & 15, quad = lane >> 4;
  const int wq = blockIdx.x + blockIdx.y * 8;    // nwg = 256
  const int xcd = wq & 7, idx = wq >> 3;         // idx in [0,32)
  const long n0 = (long)xcd * 128;
  const long m0 = (long)idx * 128;
  const int wm = (wid >> 1) * 64, wn = (wid & 1) * 64;
  const f32x4 z4 = {0.f, 0.f, 0.f, 0.f};
  f32x4 acc[4][4];
#pragma unroll
  for (int i = 0; i < 4; ++i)
#pragma unroll
    for (int j = 0; j < 4; ++j) acc[i][j] = z4;

  const int cf0 = tid, cf1 = 256 + tid;
  const int r0_ = cf0 >> 2, c0_ = (cf0 & 3) * 8;
  const int r1_ = cf1 >> 2, c1_ = (cf1 & 3) * 8;
  const __hip_bfloat16* a0 = A + (m0 + r0_) * K + c0_;
  const __hip_bfloat16* a1 = A + (m0 + r1_) * K + c1_;
  const __hip_bfloat16* b0 = BT + (n0 + r0_) * K + c0_;
  const __hip_bfloat16* b1 = BT + (n0 + r1_) * K + c1_;

  for (int k0 = 0; k0 < K; k0 += 32) {
    async16(a0 + k0, As + cf0 * 8);
    async16(a1 + k0, As + cf1 * 8);
    async16(b0 + k0, Bs + cf0 * 8);
    async16(b1 + k0, Bs + cf1 * 8);
    __syncthreads();
    bf16x8 af[4], bfv[4];
#pragma unroll
    for (int i = 0; i < 4; ++i)
      af[i] = *(const bf16x8*)(As + (wm + i * 16 + lo) * 32 + quad * 8);
#pragma unroll
    for (int i = 0; i < 4; ++i)
      bfv[i] = *(const bf16x8*)(Bs + (wn + i * 16 + lo) * 32 + quad * 8);
#pragma unroll
    for (int i = 0; i < 4; ++i)
#pragma unroll
      for (int j = 0; j < 4; ++j) acc[i][j] = MFMA16(af[i], bfv[j], acc[i][j]);
    __syncthreads();
  }
#pragma unroll
  for (int i = 0; i < 4; ++i)
#pragma unroll
    for (int j = 0; j < 4; ++j)
#pragma unroll
      for (int r = 0; r < 4; ++r) {
        long row = m0 + wm + i * 16 + quad * 4 + r;
        long col = n0 + wn + j * 16 + lo;          // [0,1024)
        float v = acc[i][j][r];
        if (col < 512)
          kf[row * 512 + col] = v;
        else
          vraw[row * 512 + (col - 512)] = __float2bfloat16(v);
      }
}

// --------------------------------------- V -> swizzled LDS-image layout
__global__ __launch_bounds__(256) void v_swizzle(const __hip_bfloat16* __restrict__ vraw,
                                                 __hip_bfloat16* __restrict__ vsw) {
  const int ktt = blockIdx.x, kvh = blockIdx.y, tid = threadIdx.x;
  __shared__ __hip_bfloat16 L[64 * 264];
#pragma unroll
  for (int it = 0; it < 8; ++it) {
    int cf = it * 256 + tid;           // 2048 chunks of 8 elems
    int kv = cf >> 5, d0 = (cf & 31) * 8;
    *(uint4*)&L[kv * 264 + d0] =
        *(const uint4*)&vraw[(((long)ktt * 64 + kv) * NKV_SZ + kvh) * 256 + d0];
  }
  __syncthreads();
#pragma unroll
  for (int it = 0; it < 8; ++it) {
    int cf = it * 256 + tid;           // c in [0,8), d in [0,256)
    int c = cf >> 8, d = cf & 255;
    union { __hip_bfloat16 h[8]; uint4 u; } t;
#pragma unroll
    for (int e = 0; e < 8; ++e) t.h[e] = L[(c * 8 + e) * 264 + d];
    *(uint4*)&vsw[((long)kvh * 64 + ktt) * 16384 + (long)(c * 256 + d) * 8] = t.u;
  }
}

// ---- K-only RMSNorm + RoPE, wave-per-row (no LDS, no barriers). 4 rows/block.
// kf (T,2,256) fp32 -> ksw 32-row tiles [kvh][tt=t/32][c=d/8][r=t%32][e=d%8].
__global__ __launch_bounds__(256) void norm_rope_k(const float* __restrict__ kbuf,
                                                   __hip_bfloat16* __restrict__ ksw,
                                                   const int* __restrict__ pos,
                                                   const float* __restrict__ kw) {
  const int id = blockIdx.x * 4 + (threadIdx.x >> 6);   // row id in [0, 8192)
  const int lane = threadIdx.x & 63;
  const int kv = id & 1, t = id >> 1;
  const float* ptr = kbuf + ((long)t * NKV_SZ + kv) * 256;
  float4 v = *(const float4*)(ptr + lane * 4);   // d = lane*4 + j
  float4 wv = *(const float4*)(kw + lane * 4);
  float s2 = v.x * v.x + v.y * v.y + v.z * v.z + v.w * v.w;
#pragma unroll
  for (int o = 32; o > 0; o >>= 1) s2 += __shfl_xor(s2, o);
  float sc = rsqrtf(s2 * (1.0f / 256.0f) + EPS_);
  float n[4];
  n[0] = v.x * sc * (1.0f + wv.x);
  n[1] = v.y * sc * (1.0f + wv.y);
  n[2] = v.z * sc * (1.0f + wv.z);
  n[3] = v.w * sc * (1.0f + wv.w);
  float pr[4];
#pragma unroll
  for (int j = 0; j < 4; ++j) pr[j] = __shfl_xor(n[j], 8);
  float o4[4];
  if (lane < 16) {
    int base_i = (lane & 7) * 4;
#pragma unroll
    for (int j = 0; j < 4; ++j) {
      int i = base_i + j;
      float p = (float)pos[(i % 3) * T_SZ + t];
      float fr = p * exp2f((float)i * (-0.72667177075661f));  // 1e7^(-i/32)
      float c, s;
      sincosf(fr, &s, &c);
      o4[j] = (lane < 8) ? n[j] * c - pr[j] * s : n[j] * c + pr[j] * s;
    }
  } else {
#pragma unroll
    for (int j = 0; j < 4; ++j) o4[j] = n[j];
  }
  long tt = t >> 5; int r = t & 31;
  int c = lane >> 1, e0 = (lane & 1) * 4;
  union { __hip_bfloat16 h4[4]; uint2 u; } kk;
#pragma unroll
  for (int j = 0; j < 4; ++j) kk.h4[j] = __float2bfloat16(o4[j]);
  *(uint2*)&ksw[(((long)kv * 128 + tt) * 32 + c) * 256 + r * 8 + e0] = kk.u;
}

// ------------------------------------------------------- flash causal attention
__global__ __launch_bounds__(256) void attn_kernel(unsigned* __restrict__ Qp,
                                                   const __hip_bfloat16* __restrict__ Ksw,
                                                   const __hip_bfloat16* __restrict__ Vsw,
                                                   const __hip_bfloat16* __restrict__ Gt) {
  const int w = blockIdx.x + blockIdx.y * 64;
  const int xcd = w & 7, j = w >> 3;           // j in [0,128)
  const int h = xcd * 2 + (j & 1);
  const int qt = 63 - (j >> 1);
  const int kvh = h >> 3;
  const int tid = threadIdx.x, wid = tid >> 6, lane = tid & 63;
  const int lo = lane & 15, quad = lane >> 4;
  __shared__ __align__(16) __hip_bfloat16 Ks[32 * 256];   // [c=d/8][r=kv%32][e]
  __shared__ __align__(16) __hip_bfloat16 Vs[4 * 2048];   // [cc=kv/8][d=256][e]
  __shared__ __align__(16) __hip_bfloat16 Ps[4][16 * 40]; // per-wave 16x32, stride 40

  __hip_bfloat16* myP = &Ps[wid][0];
  const f32x4 z4 = {0.f, 0.f, 0.f, 0.f};
  const int nt = 2 * (qt + 1);                 // 32-row KV tiles

  bf16x8 qh[8], ql[8];
  {
    const unsigned* qp =
        Qp + ((long)(qt * 64 + wid * 16 + lo) * NH_SZ + h) * 256 + quad * 8;
#pragma unroll
    for (int kc = 0; kc < 8; ++kc) {
      uint4 p0 = *(const uint4*)(qp + kc * 32);
      uint4 p1 = *(const uint4*)(qp + kc * 32 + 4);
      bf16x8 a, b;
      a[0] = (short)(p0.x & 0xffff); b[0] = (short)(p0.x >> 16);
      a[1] = (short)(p0.y & 0xffff); b[1] = (short)(p0.y >> 16);
      a[2] = (short)(p0.z & 0xffff); b[2] = (short)(p0.z >> 16);
      a[3] = (short)(p0.w & 0xffff); b[3] = (short)(p0.w >> 16);
      a[4] = (short)(p1.x & 0xffff); b[4] = (short)(p1.x >> 16);
      a[5] = (short)(p1.y & 0xffff); b[5] = (short)(p1.y >> 16);
      a[6] = (short)(p1.z & 0xffff); b[6] = (short)(p1.z >> 16);
      a[7] = (short)(p1.w & 0xffff); b[7] = (short)(p1.w >> 16);
      qh[kc] = a; ql[kc] = b;
    }
  }

  f32x4 acc[16];
#pragma unroll
  for (int od = 0; od < 16; ++od) acc[od] = z4;
  float lsum[4];
#pragma unroll
  for (int r = 0; r < 4; ++r) lsum[r] = 0.f;

  const int qrow_g = qt * 64 + wid * 16 + quad * 4;
  const __hip_bfloat16* kbase = Ksw + (long)kvh * 1048576;  // 128 tiles * 8192
  const __hip_bfloat16* vbase = Vsw + (long)kvh * 1048576;

#pragma unroll
  for (int i = 0; i < 4; ++i) {
    int m = i * 4 + wid;
    async16(kbase + m * 512 + lane * 8, Ks + m * 512 + lane * 8);
    async16(vbase + m * 512 + lane * 8, Vs + m * 512 + lane * 8);
  }
  __syncthreads();  // drain K(0), V(0)

  for (int kt = 0; kt < nt; ++kt) {
    const bool skip = (kt == nt - 1) && (wid < 2);
    f32x4 s[2];
    s[0] = z4; s[1] = z4;
    if (!skip) {
      __builtin_amdgcn_s_setprio(1);
#pragma unroll
      for (int kc = 0; kc < 8; ++kc) {
        bf16x8 ah = qh[kc], al = ql[kc];
#pragma unroll
        for (int ni = 0; ni < 2; ++ni) {
          bf16x8 b = *(const bf16x8*)(Ks + (kc * 4 + quad) * 256 + (ni * 16 + lo) * 8);
          s[ni] = MFMA16(ah, b, s[ni]);
          s[ni] = MFMA16(al, b, s[ni]);
        }
      }
      __builtin_amdgcn_s_setprio(0);
    }
    __syncthreads();  // B: Ks(kt) reads done; drains V(kt) prefetch
    if (kt + 1 < nt) {
      const __hip_bfloat16* kb = kbase + (long)(kt + 1) * 8192;
#pragma unroll
      for (int i = 0; i < 4; ++i) {
        int m = i * 4 + wid;
        async16(kb + m * 512 + lane * 8, Ks + m * 512 + lane * 8);
      }
    }
    if (!skip) {
      float sv[2][4];
      if (kt >= nt - 2) {
#pragma unroll
        for (int ni = 0; ni < 2; ++ni) {
          int kcol = kt * 32 + ni * 16 + lo;
#pragma unroll
          for (int r = 0; r < 4; ++r) {
            float e = __expf(fmaf(s[ni][r], ATT_SCALE, -SOFT_M));
            sv[ni][r] = (kcol > qrow_g + r) ? 0.f : e;
          }
        }
      } else {
#pragma unroll
        for (int ni = 0; ni < 2; ++ni)
#pragma unroll
          for (int r = 0; r < 4; ++r)
            sv[ni][r] = __expf(fmaf(s[ni][r], ATT_SCALE, -SOFT_M));
      }
#pragma unroll
      for (int r = 0; r < 4; ++r) lsum[r] += sv[0][r] + sv[1][r];
#pragma unroll
      for (int ni = 0; ni < 2; ++ni)
#pragma unroll
        for (int r = 0; r < 4; ++r)
          myP[(quad * 4 + r) * 40 + ni * 16 + lo] = __float2bfloat16(sv[ni][r]);
      bf16x8 ap = *(const bf16x8*)(myP + lo * 40 + quad * 8);
      __builtin_amdgcn_s_setprio(1);
#pragma unroll
      for (int od = 0; od < 16; ++od) {
        bf16x8 bv = *(const bf16x8*)(Vs + quad * 2048 + (od * 16 + lo) * 8);
        acc[od] = MFMA16(ap, bv, acc[od]);
      }
      __builtin_amdgcn_s_setprio(0);
    }
    __syncthreads();  // C: Vs(kt) reads done; drains K(kt+1) prefetch
    if (kt + 1 < nt) {
      const __hip_bfloat16* vb = vbase + (long)(kt + 1) * 8192;
#pragma unroll
      for (int i = 0; i < 4; ++i) {
        int m = i * 4 + wid;
        async16(vb + m * 512 + lane * 8, Vs + m * 512 + lane * 8);
      }
    }
  }

  float l_r[4];
#pragma unroll
  for (int r = 0; r < 4; ++r) {
    float su = lsum[r];
#pragma unroll
    for (int off = 1; off < 16; off <<= 1) su += __shfl_xor(su, off);
    l_r[r] = su;
  }
#pragma unroll
  for (int od = 0; od < 16; ++od)
#pragma unroll
    for (int r = 0; r < 4; ++r) {
      int trow = qt * 64 + wid * 16 + quad * 4 + r;
      int col = od * 16 + lo;
      long idx = ((long)trow * NH_SZ + h) * 256 + col;
      float g = __bfloat162float(Gt[idx]);
      float sig = 1.0f / (1.0f + expf(-g));
      float v = (acc[od][r] / l_r[r]) * sig;
      Qp[idx] = pack_hilo(v);
    }
}

// ------------------- out GEMM: A packed hi/lo (2-pass), B bf16, fp32 out
// (Proven fastest variant: rounds 6-7 deep-pipeline replacements were slower.)
__global__ __launch_bounds__(256) void gemm_out(const unsigned* __restrict__ Ap,
                                                const __hip_bfloat16* __restrict__ Bt,
                                                float* __restrict__ C,
                                                int M, int N, int K) {
  __shared__ __align__(16) __hip_bfloat16 Ash[128 * 32];
  __shared__ __align__(16) __hip_bfloat16 Asl[128 * 32];
  __shared__ __align__(16) __hip_bfloat16 Bs[128 * 32];
  const int tid = threadIdx.x;
  const int wid = tid >> 6, lane = tid & 63;
  const int lo = lane & 15, quad = lane >> 4;
  const int wq = blockIdx.x + blockIdx.y * 16;   // nwg = 512
  const int xcd = wq & 7, idx = wq >> 3;         // idx in [0,64)
  const long n0 = (long)(xcd * 2 + (idx & 1)) * 128;
  const long m0 = (long)(idx >> 1) * 128;
  const int wm = (wid >> 1) * 64, wn = (wid & 1) * 64;
  const f32x4 z4 = {0.f, 0.f, 0.f, 0.f};
  f32x4 acc[4][4];
#pragma unroll
  for (int i = 0; i < 4; ++i)
#pragma unroll
    for (int j = 0; j < 4; ++j) acc[i][j] = z4;

  const int cf0 = tid, cf1 = 256 + tid;
  const int br0 = cf0 >> 2, bc0 = (cf0 & 3) * 8;
  const int br1 = cf1 >> 2, bc1 = (cf1 & 3) * 8;
  const __hip_bfloat16* b0 = Bt + (n0 + br0) * K + bc0;
  const __hip_bfloat16* b1 = Bt + (n0 + br1) * K + bc1;

  for (int k0 = 0; k0 < K; k0 += 32) {
    async16(b0 + k0, Bs + cf0 * 8);
    async16(b1 + k0, Bs + cf1 * 8);
#pragma unroll
    for (int it = 0; it < 4; ++it) {
      int c = it * 256 + tid, row = c >> 3, c4 = (c & 7) * 4;
      uint4 p = *(const uint4*)(Ap + (m0 + row) * K + k0 + c4);
      uint2 wh, wl;
      wh.x = (p.x & 0xffff) | ((p.y & 0xffff) << 16);
      wh.y = (p.z & 0xffff) | ((p.w & 0xffff) << 16);
      wl.x = (p.x >> 16) | (p.y & 0xffff0000u);
      wl.y = (p.z >> 16) | (p.w & 0xffff0000u);
      *(uint2*)(Ash + row * 32 + c4) = wh;
      *(uint2*)(Asl + row * 32 + c4) = wl;
    }
    __syncthreads();
    bf16x8 ah[4], al[4], bf[4];
#pragma unroll
    for (int i = 0; i < 4; ++i) {
      ah[i] = *(const bf16x8*)(Ash + (wm + i * 16 + lo) * 32 + quad * 8);
      al[i] = *(const bf16x8*)(Asl + (wm + i * 16 + lo) * 32 + quad * 8);
      bf[i] = *(const bf16x8*)(Bs + (wn + i * 16 + lo) * 32 + quad * 8);
    }
#pragma unroll
    for (int i = 0; i < 4; ++i)
#pragma unroll
      for (int j = 0; j < 4; ++j) {
        acc[i][j] = MFMA16(ah[i], bf[j], acc[i][j]);
        acc[i][j] = MFMA16(al[i], bf[j], acc[i][j]);
      }
    __syncthreads();
  }
#pragma unroll
  for (int i = 0; i < 4; ++i)
#pragma unroll
    for (int j = 0; j < 4; ++j)
#pragma unroll
      for (int r = 0; r < 4; ++r) {
        long row = m0 + wm + i * 16 + quad * 4 + r;
        long col = n0 + wn + j * 16 + lo;
        C[row * N + col] = acc[i][j][r];
      }
}

// ------------------------------------------------------------------- launcher
extern "C" void kernel_launch(void* const* d_in, const int* in_sizes, int n_in,
                              void* d_out, int out_size, void* d_ws, size_t ws_size,
                              hipStream_t stream) {
  (void)in_sizes; (void)n_in; (void)out_size; (void)ws_size;
  const int* positions = (const int*)d_in[0];
  const float* hidden = (const float*)d_in[1];
  const float* Wq = (const float*)d_in[2];
  const float* Wk = (const float*)d_in[3];
  const float* Wv = (const float*)d_in[4];
  const float* Wo = (const float*)d_in[5];
  const float* qw = (const float*)d_in[6];
  const float* kw = (const float*)d_in[7];
  float* out = (float*)d_out;
  char* ws = (char*)d_ws;

  // layout (bytes), total exactly 160 MiB:
  __hip_bfloat16* hid  = (__hip_bfloat16*)(ws + 0);           // 16 MB (dead after GEMMs)
  __hip_bfloat16* WqT  = (__hip_bfloat16*)(ws + 16777216);    // 32 MB
  __hip_bfloat16* WkT  = (__hip_bfloat16*)(ws + 50331648);    //  2 MB  (WvT contiguous after)
  __hip_bfloat16* WvT  = (__hip_bfloat16*)(ws + 52428800);    //  2 MB
  float*          qf   = (float*)(ws + 54525952);             // 64 MB region: packed q/o (32 MB used)
  __hip_bfloat16* gate = (__hip_bfloat16*)(ws + 121634816);   // 32 MB (T,16,256)
  float*          kf   = (float*)(ws + 155189248);            //  8 MB (T,2,256) fp32
  __hip_bfloat16* vraw = (__hip_bfloat16*)(ws + 163577856);   //  4 MB -> end 167,772,160
  __hip_bfloat16* Ksw  = WkT;                                  // alias 4 MB [WkT+WvT] after kv GEMM
  __hip_bfloat16* Vsw  = hid;                                  // alias 4 MB of hid after GEMMs
  __hip_bfloat16* WoT  = gate;                                 // alias gate region after attn
  unsigned* qpk = (unsigned*)qf;

  // 1) casts / transposes
  cast_f32_bf16<<<dim3(8192), dim3(256), 0, stream>>>(hidden, hid, 2097152);
  transpose_cast<float><<<dim3(256, 64), dim3(256), 0, stream>>>(Wq, WqT, 2048, 8192);
  transpose_cast<float><<<dim3(16, 64), dim3(256), 0, stream>>>(Wk, WkT, 2048, 512);
  transpose_cast<float><<<dim3(16, 64), dim3(256), 0, stream>>>(Wv, WvT, 2048, 512);
  // 2) projections: q packed+RoPE'd directly (fused epilogue) + gate; fused k/v
  gemm_qg2<<<dim3(8, 64), dim3(512), 0, stream>>>(hid, WqT, qpk, gate, positions, qw);
  gemm_kv<<<dim3(8, 32), dim3(256), 0, stream>>>(hid, WkT, kf, vraw, 4096, 1024, 2048);
  // 3) V -> swizzled (after GEMMs: Vsw aliases hid)
  v_swizzle<<<dim3(64, 2), dim3(256), 0, stream>>>(vraw, Vsw);
  // 4) K-only RMSNorm + RoPE -> swizzled Ksw (q path fused into gemm_qg2)
  norm_rope_k<<<dim3(2048), dim3(256), 0, stream>>>(kf, Ksw, positions, kw);
  // 5) flash attention, one q-tile per block, big-first + XCD swizzle
  attn_kernel<<<dim3(64, 16), dim3(256), 0, stream>>>(qpk, Ksw, Vsw, gate);
  // 6) Wo -> bf16 transpose (into dead gate region), then 2-pass out GEMM
  transpose_cast<float><<<dim3(64, 128), dim3(256), 0, stream>>>(Wo, WoT, 4096, 2048);
  gemm_out<<<dim3(16, 32), dim3(256), 0, stream>>>(qpk, WoT, out, 4096, 2048, 4096);
}

// Round 9
// 797.527 us; speedup vs baseline: 1.0807x; 1.0361x over previous
//
#include <hip/hip_runtime.h>
#include <hip/hip_bf16.h>

// Qwen3.5 attention block: T=4096, H=2048, NH=16, NKV=2, HD=256, ROT=64
// bf16 MFMA (16x16x32) with fp32 accumulate; precision-critical intermediates
// kept fp32 or split into bf16 hi/lo pairs (packed ushort2 in 4B slots).
// Attn: KV tile = 32 rows, LDS 37888B -> 3 blocks/CU, rotated prefetch.
// gemm_qg2: deep-pipeline 4-deep LDS ring, counted vmcnt, 1 barrier/K-tile,
// XOR-swizzled staging, XCD n-panel grouping, FUSED q-RMSNorm+RoPE+pack
// epilogue. RoPE trig comes from a precomputed 1MB table (tab[t][i]=cos,sin)
// stored in d_out scratch (dead until final gemm_out overwrites it) -- the
// round-8 fused epilogue paid ~27us of serial sincosf tail; table loads
// remove it while keeping the fusion's 96MB traffic saving.
// Output GEMM: proven 2-barrier hi/lo 2-pass (deep-pipeline variants were
// A/B-tested slower in rounds 6-7).

#define T_SZ 4096
#define H_SZ 2048
#define NH_SZ 16
#define NKV_SZ 2
#define HD_SZ 256
#define ATT_SCALE 0.0625f   // HD^-0.5
#define SOFT_M 18.0f        // fixed softmax shift
#define EPS_ 1e-6f

typedef __attribute__((ext_vector_type(8))) short bf16x8;   // 8 bf16 = 4 VGPRs
typedef __attribute__((ext_vector_type(4))) float f32x4;

#define MFMA16(a, b, c) __builtin_amdgcn_mfma_f32_16x16x32_bf16((a), (b), (c), 0, 0, 0)

__device__ __forceinline__ void async16(const void* g, void* l) {
  __builtin_amdgcn_global_load_lds((const __attribute__((address_space(1))) void*)g,
                                   (__attribute__((address_space(3))) void*)l,
                                   16, 0, 0);
}

__device__ __forceinline__ float to_f(float x) { return x; }
__device__ __forceinline__ float to_f(__hip_bfloat16 x) { return __bfloat162float(x); }

union BfBits { __hip_bfloat16 h; unsigned short u; };

__device__ __forceinline__ unsigned short bf16_bits(__hip_bfloat16 h) {
  BfBits t; t.h = h; return t.u;
}

__device__ __forceinline__ unsigned pack_hilo(float v) {
  __hip_bfloat16 hi = __float2bfloat16(v);
  float rem = v - __bfloat162float(hi);
  __hip_bfloat16 lo = __float2bfloat16(rem);
  return (unsigned)bf16_bits(hi) | ((unsigned)bf16_bits(lo) << 16);
}

// ---------------- RoPE cos/sin table: tab[t*32+i] = (cos, sin) of
// pos[i%3][t] * 1e7^(-i/32). 4096x32 float2 = 1MB, lives in d_out scratch.
__global__ __launch_bounds__(256) void rope_table(const int* __restrict__ pos,
                                                  float2* __restrict__ tab) {
  int id = blockIdx.x * 256 + threadIdx.x;   // [0, 131072)
  int t = id >> 5, i = id & 31;
  float p = (float)pos[(i % 3) * T_SZ + t];
  float fr = p * exp2f((float)i * (-0.72667177075661f));  // 1e7^(-i/32)
  float c, s;
  sincosf(fr, &s, &c);
  tab[id] = make_float2(c, s);
}

// ---------------------------------------------------------------- cast hidden
__global__ __launch_bounds__(256) void cast_f32_bf16(const float* __restrict__ in,
                                                     __hip_bfloat16* __restrict__ out,
                                                     int n4) {
  int i = blockIdx.x * 256 + threadIdx.x;
  if (i >= n4) return;
  float4 v = ((const float4*)in)[i];
  union { __hip_bfloat16 h[4]; uint2 u; } t;
  t.h[0] = __float2bfloat16(v.x);
  t.h[1] = __float2bfloat16(v.y);
  t.h[2] = __float2bfloat16(v.z);
  t.h[3] = __float2bfloat16(v.w);
  ((uint2*)out)[i] = t.u;
}

// ------------------------------------------------------- transpose (+cast bf16)
template <typename TIN>
__global__ __launch_bounds__(256) void transpose_cast(const TIN* __restrict__ in,
                                                      __hip_bfloat16* __restrict__ out,
                                                      int R, int C) {
  __shared__ TIN tile[32][33];
  int c0 = blockIdx.x * 32, r0 = blockIdx.y * 32;
  int tx = threadIdx.x & 31, ty = threadIdx.x >> 5;
#pragma unroll
  for (int i = 0; i < 32; i += 8)
    tile[ty + i][tx] = in[(long)(r0 + ty + i) * C + c0 + tx];
  __syncthreads();
#pragma unroll
  for (int i = 0; i < 32; i += 8)
    out[(long)(c0 + ty + i) * R + r0 + tx] = __float2bfloat16(to_f(tile[tx][ty + i]));
}

// ---------------- Wq GEMM, deep-pipelined, with FUSED q-norm/RoPE/pack epilogue
// 256x256 tile, BK=32, 4-deep LDS ring, counted vmcnt, quad-XOR LDS swizzle.
// q blocks: RMSNorm via per-wave shfl + 4KB LDS cross-wave reduce, RoPE via
// table loads (pairs fn<->fn+2 same-lane, wn==0 waves only), pack_hilo store.
__global__ __launch_bounds__(512) void gemm_qg2(const __hip_bfloat16* __restrict__ A,
                                                const __hip_bfloat16* __restrict__ BT,
                                                unsigned* __restrict__ qpk,
                                                __hip_bfloat16* __restrict__ gate,
                                                const float2* __restrict__ tab,
                                                const float* __restrict__ qw) {
  __shared__ __align__(16) __hip_bfloat16 As[4][8192];  // [buf][kcslot 4][row 256][e 8]
  __shared__ __align__(16) __hip_bfloat16 Bs[4][8192];
  const int tid = threadIdx.x, wid = tid >> 6, lane = tid & 63;
  const int lo = lane & 15, quad = lane >> 4;
  const int wm = (wid >> 2) * 128, wn = (wid & 3) * 64;  // 2m x 4n waves
  const int wnx = wid & 3;
  const int wg = blockIdx.x + blockIdx.y * 8;            // 512 wgs
  const int xcd = wg & 7, i_ = wg >> 3;                  // i_ in [0,64)
  const long n0 = (long)(xcd * 4 + (i_ & 3)) * 256;      // 4 B-panels (4MB) per XCD
  const long m0 = (long)(i_ >> 2) * 256;
  const int K = 2048;

  const int r0_ = tid >> 2;                       // rows 0..127 (load0), +128 (load1)
  const int kc0 = (tid & 3) ^ ((tid >> 3) & 3);   // slot ^ ((row>>1)&3)
  const __hip_bfloat16* sA0 = A + (m0 + r0_) * K + kc0 * 8;
  const __hip_bfloat16* sA1 = A + (m0 + r0_ + 128) * K + kc0 * 8;
  const __hip_bfloat16* sB0 = BT + (n0 + r0_) * K + kc0 * 8;
  const __hip_bfloat16* sB1 = BT + (n0 + r0_ + 128) * K + kc0 * 8;

  const int xq = (lo >> 1) & 3;
  const int aoff = (wm + lo) * 32 + ((quad ^ xq) * 8);
  const int boff = (wn + lo) * 32 + ((quad ^ xq) * 8);

  const f32x4 z4 = {0.f, 0.f, 0.f, 0.f};
  f32x4 acc[8][4];
#pragma unroll
  for (int fr = 0; fr < 8; ++fr)
#pragma unroll
    for (int fn = 0; fn < 4; ++fn) acc[fr][fn] = z4;

#define QG_STAGE(buf, kt) do {                                   \
    const int off_ = (kt) * 32;                                  \
    async16(sA0 + off_, &As[buf][tid * 8]);                      \
    async16(sA1 + off_, &As[buf][tid * 8 + 4096]);               \
    async16(sB0 + off_, &Bs[buf][tid * 8]);                      \
    async16(sB1 + off_, &Bs[buf][tid * 8 + 4096]);               \
  } while (0)

#define QG_COMPUTE(buf_) do {                                    \
    bf16x8 af[8], bq[4];                                         \
    _Pragma("unroll")                                            \
    for (int fr = 0; fr < 8; ++fr)                               \
      af[fr] = *(const bf16x8*)(&As[buf_][aoff + fr * 512]);     \
    _Pragma("unroll")                                            \
    for (int fn = 0; fn < 4; ++fn)                               \
      bq[fn] = *(const bf16x8*)(&Bs[buf_][boff + fn * 512]);     \
    __builtin_amdgcn_s_setprio(1);                               \
    _Pragma("unroll")                                            \
    for (int fr = 0; fr < 8; ++fr)                               \
      _Pragma("unroll")                                          \
      for (int fn = 0; fn < 4; ++fn)                             \
        acc[fr][fn] = MFMA16(af[fr], bq[fn], acc[fr][fn]);       \
    __builtin_amdgcn_s_setprio(0);                               \
  } while (0)

  QG_STAGE(0, 0); QG_STAGE(1, 1); QG_STAGE(2, 2);
  for (int kt = 0; kt < 61; ++kt) {
    asm volatile("s_waitcnt vmcnt(8)" ::: "memory");
    __builtin_amdgcn_s_barrier();
    __builtin_amdgcn_sched_barrier(0);
    QG_STAGE((kt + 3) & 3, kt + 3);
    __builtin_amdgcn_sched_barrier(0);
    QG_COMPUTE(kt & 3);
  }
  asm volatile("s_waitcnt vmcnt(8)" ::: "memory");
  __builtin_amdgcn_s_barrier();
  __builtin_amdgcn_sched_barrier(0);
  QG_COMPUTE(1);   // kt=61
  asm volatile("s_waitcnt vmcnt(4)" ::: "memory");
  __builtin_amdgcn_s_barrier();
  __builtin_amdgcn_sched_barrier(0);
  QG_COMPUTE(2);   // kt=62
  asm volatile("s_waitcnt vmcnt(0)" ::: "memory");
  __builtin_amdgcn_s_barrier();
  __builtin_amdgcn_sched_barrier(0);
  QG_COMPUTE(3);   // kt=63
#undef QG_STAGE
#undef QG_COMPUTE

  const int head = (int)(n0 >> 9);
  const bool isq = ((n0 >> 8) & 1) == 0;
  if (!isq) {
    // ---- gate half: plain bf16 store (c-256 = wn + fn*16 + lo)
#pragma unroll
    for (int fr = 0; fr < 8; ++fr)
#pragma unroll
      for (int fn = 0; fn < 4; ++fn)
#pragma unroll
        for (int rr = 0; rr < 4; ++rr) {
          long row = m0 + wm + fr * 16 + quad * 4 + rr;
          int c = wn + fn * 16 + lo;
          gate[(row * NH_SZ + head) * 256 + c] = __float2bfloat16(acc[fr][fn][rr]);
        }
  } else {
    // ---- q half: fused RMSNorm + RoPE(table) + hi/lo pack
    __syncthreads();                       // all frag reads done; reuse As as scratch
    float* red = (float*)&As[0][0];        // [256 rows][4 wn] floats = 4KB
#pragma unroll
    for (int fr = 0; fr < 8; ++fr)
#pragma unroll
      for (int rr = 0; rr < 4; ++rr) {
        float p = 0.f;
#pragma unroll
        for (int fn = 0; fn < 4; ++fn) { float x = acc[fr][fn][rr]; p += x * x; }
#pragma unroll
        for (int off = 1; off < 16; off <<= 1) p += __shfl_xor(p, off);
        if (lo == 0) red[(wm + fr * 16 + quad * 4 + rr) * 4 + wnx] = p;
      }
    __syncthreads();
    float wq4[4];
#pragma unroll
    for (int fn = 0; fn < 4; ++fn) wq4[fn] = 1.0f + qw[wn + fn * 16 + lo];
#pragma unroll
    for (int fr = 0; fr < 8; ++fr)
#pragma unroll
      for (int rr = 0; rr < 4; ++rr) {
        int rl = wm + fr * 16 + quad * 4 + rr;
        float4 rv = *(const float4*)&red[rl * 4];
        float sc = rsqrtf((rv.x + rv.y + rv.z + rv.w) * (1.0f / 256.0f) + EPS_);
        float v[4];
#pragma unroll
        for (int fn = 0; fn < 4; ++fn) v[fn] = acc[fr][fn][rr] * sc * wq4[fn];
        long row = m0 + rl;                // token t
        if (wnx == 0) {
          // RoPE on cols 0..63: pairs (d, d+32) == (fn, fn+2) same lane
#pragma unroll
          for (int fnp = 0; fnp < 2; ++fnp) {
            int i = fnp * 16 + lo;         // freq index 0..31
            float2 cs = tab[row * 32 + i];
            float x1 = v[fnp], x2 = v[fnp + 2];
            v[fnp] = x1 * cs.x - x2 * cs.y;
            v[fnp + 2] = x2 * cs.x + x1 * cs.y;
          }
        }
        long base = (row * NH_SZ + head) * 256;
#pragma unroll
        for (int fn = 0; fn < 4; ++fn)
          qpk[base + wn + fn * 16 + lo] = pack_hilo(v[fn]);
      }
  }
}

// --------------------------- fused K+V projection GEMM (N=1024; WkT||WvT rows)
__global__ __launch_bounds__(256) void gemm_kv(const __hip_bfloat16* __restrict__ A,
                                               const __hip_bfloat16* __restrict__ BT,
                                               float* __restrict__ kf,
                                               __hip_bfloat16* __restrict__ vraw,
                                               int M, int N, int K) {
  __shared__ __align__(16) __hip_bfloat16 As[128 * 32];
  __shared__ __align__(16) __hip_bfloat16 Bs[128 * 32];
  const int tid = threadIdx.x;
  const int wid = tid >> 6, lane = tid & 63;
  const int lo = lane & 15, quad = lane >> 4;
  const int wq = blockIdx.x + blockIdx.y * 8;    // nwg = 256
  const int xcd = wq & 7, idx = wq >> 3;         // idx in [0,32)
  const long n0 = (long)xcd * 128;
  const long m0 = (long)idx * 128;
  const int wm = (wid >> 1) * 64, wn = (wid & 1) * 64;
  const f32x4 z4 = {0.f, 0.f, 0.f, 0.f};
  f32x4 acc[4][4];
#pragma unroll
  for (int i = 0; i < 4; ++i)
#pragma unroll
    for (int j = 0; j < 4; ++j) acc[i][j] = z4;

  const int cf0 = tid, cf1 = 256 + tid;
  const int r0_ = cf0 >> 2, c0_ = (cf0 & 3) * 8;
  const int r1_ = cf1 >> 2, c1_ = (cf1 & 3) * 8;
  const __hip_bfloat16* a0 = A + (m0 + r0_) * K + c0_;
  const __hip_bfloat16* a1 = A + (m0 + r1_) * K + c1_;
  const __hip_bfloat16* b0 = BT + (n0 + r0_) * K + c0_;
  const __hip_bfloat16* b1 = BT + (n0 + r1_) * K + c1_;

  for (int k0 = 0; k0 < K; k0 += 32) {
    async16(a0 + k0, As + cf0 * 8);
    async16(a1 + k0, As + cf1 * 8);
    async16(b0 + k0, Bs + cf0 * 8);
    async16(b1 + k0, Bs + cf1 * 8);
    __syncthreads();
    bf16x8 af[4], bfv[4];
#pragma unroll
    for (int i = 0; i < 4; ++i)
      af[i] = *(const bf16x8*)(As + (wm + i * 16 + lo) * 32 + quad * 8);
#pragma unroll
    for (int i = 0; i < 4; ++i)
      bfv[i] = *(const bf16x8*)(Bs + (wn + i * 16 + lo) * 32 + quad * 8);
#pragma unroll
    for (int i = 0; i < 4; ++i)
#pragma unroll
      for (int j = 0; j < 4; ++j) acc[i][j] = MFMA16(af[i], bfv[j], acc[i][j]);
    __syncthreads();
  }
#pragma unroll
  for (int i = 0; i < 4; ++i)
#pragma unroll
    for (int j = 0; j < 4; ++j)
#pragma unroll
      for (int r = 0; r < 4; ++r) {
        long row = m0 + wm + i * 16 + quad * 4 + r;
        long col = n0 + wn + j * 16 + lo;          // [0,1024)
        float v = acc[i][j][r];
        if (col < 512)
          kf[row * 512 + col] = v;
        else
          vraw[row * 512 + (col - 512)] = __float2bfloat16(v);
      }
}

// --------------------------------------- V -> swizzled LDS-image layout
__global__ __launch_bounds__(256) void v_swizzle(const __hip_bfloat16* __restrict__ vraw,
                                                 __hip_bfloat16* __restrict__ vsw) {
  const int ktt = blockIdx.x, kvh = blockIdx.y, tid = threadIdx.x;
  __shared__ __hip_bfloat16 L[64 * 264];
#pragma unroll
  for (int it = 0; it < 8; ++it) {
    int cf = it * 256 + tid;           // 2048 chunks of 8 elems
    int kv = cf >> 5, d0 = (cf & 31) * 8;
    *(uint4*)&L[kv * 264 + d0] =
        *(const uint4*)&vraw[(((long)ktt * 64 + kv) * NKV_SZ + kvh) * 256 + d0];
  }
  __syncthreads();
#pragma unroll
  for (int it = 0; it < 8; ++it) {
    int cf = it * 256 + tid;           // c in [0,8), d in [0,256)
    int c = cf >> 8, d = cf & 255;
    union { __hip_bfloat16 h[8]; uint4 u; } t;
#pragma unroll
    for (int e = 0; e < 8; ++e) t.h[e] = L[(c * 8 + e) * 264 + d];
    *(uint4*)&vsw[((long)kvh * 64 + ktt) * 16384 + (long)(c * 256 + d) * 8] = t.u;
  }
}

// ---- K-only RMSNorm + RoPE(table), wave-per-row (no LDS/barriers). 4 rows/blk.
// kf (T,2,256) fp32 -> ksw 32-row tiles [kvh][tt=t/32][c=d/8][r=t%32][e=d%8].
__global__ __launch_bounds__(256) void norm_rope_k(const float* __restrict__ kbuf,
                                                   __hip_bfloat16* __restrict__ ksw,
                                                   const float2* __restrict__ tab,
                                                   const float* __restrict__ kw) {
  const int id = blockIdx.x * 4 + (threadIdx.x >> 6);   // row id in [0, 8192)
  const int lane = threadIdx.x & 63;
  const int kv = id & 1, t = id >> 1;
  const float* ptr = kbuf + ((long)t * NKV_SZ + kv) * 256;
  float4 v = *(const float4*)(ptr + lane * 4);   // d = lane*4 + j
  float4 wv = *(const float4*)(kw + lane * 4);
  float s2 = v.x * v.x + v.y * v.y + v.z * v.z + v.w * v.w;
#pragma unroll
  for (int o = 32; o > 0; o >>= 1) s2 += __shfl_xor(s2, o);
  float sc = rsqrtf(s2 * (1.0f / 256.0f) + EPS_);
  float n[4];
  n[0] = v.x * sc * (1.0f + wv.x);
  n[1] = v.y * sc * (1.0f + wv.y);
  n[2] = v.z * sc * (1.0f + wv.z);
  n[3] = v.w * sc * (1.0f + wv.w);
  float pr[4];
#pragma unroll
  for (int j = 0; j < 4; ++j) pr[j] = __shfl_xor(n[j], 8);
  float o4[4];
  if (lane < 16) {
    int base_i = (lane & 7) * 4;
#pragma unroll
    for (int j = 0; j < 4; ++j) {
      int i = base_i + j;
      float2 cs = tab[(long)t * 32 + i];
      o4[j] = (lane < 8) ? n[j] * cs.x - pr[j] * cs.y
                         : n[j] * cs.x + pr[j] * cs.y;
    }
  } else {
#pragma unroll
    for (int j = 0; j < 4; ++j) o4[j] = n[j];
  }
  long tt = t >> 5; int r = t & 31;
  int c = lane >> 1, e0 = (lane & 1) * 4;
  union { __hip_bfloat16 h4[4]; uint2 u; } kk;
#pragma unroll
  for (int j = 0; j < 4; ++j) kk.h4[j] = __float2bfloat16(o4[j]);
  *(uint2*)&ksw[(((long)kv * 128 + tt) * 32 + c) * 256 + r * 8 + e0] = kk.u;
}

// ------------------------------------------------------- flash causal attention
__global__ __launch_bounds__(256) void attn_kernel(unsigned* __restrict__ Qp,
                                                   const __hip_bfloat16* __restrict__ Ksw,
                                                   const __hip_bfloat16* __restrict__ Vsw,
                                                   const __hip_bfloat16* __restrict__ Gt) {
  const int w = blockIdx.x + blockIdx.y * 64;
  const int xcd = w & 7, j = w >> 3;           // j in [0,128)
  const int h = xcd * 2 + (j & 1);
  const int qt = 63 - (j >> 1);
  const int kvh = h >> 3;
  const int tid = threadIdx.x, wid = tid >> 6, lane = tid & 63;
  const int lo = lane & 15, quad = lane >> 4;
  __shared__ __align__(16) __hip_bfloat16 Ks[32 * 256];   // [c=d/8][r=kv%32][e]
  __shared__ __align__(16) __hip_bfloat16 Vs[4 * 2048];   // [cc=kv/8][d=256][e]
  __shared__ __align__(16) __hip_bfloat16 Ps[4][16 * 40]; // per-wave 16x32, stride 40

  __hip_bfloat16* myP = &Ps[wid][0];
  const f32x4 z4 = {0.f, 0.f, 0.f, 0.f};
  const int nt = 2 * (qt + 1);                 // 32-row KV tiles

  bf16x8 qh[8], ql[8];
  {
    const unsigned* qp =
        Qp + ((long)(qt * 64 + wid * 16 + lo) * NH_SZ + h) * 256 + quad * 8;
#pragma unroll
    for (int kc = 0; kc < 8; ++kc) {
      uint4 p0 = *(const uint4*)(qp + kc * 32);
      uint4 p1 = *(const uint4*)(qp + kc * 32 + 4);
      bf16x8 a, b;
      a[0] = (short)(p0.x & 0xffff); b[0] = (short)(p0.x >> 16);
      a[1] = (short)(p0.y & 0xffff); b[1] = (short)(p0.y >> 16);
      a[2] = (short)(p0.z & 0xffff); b[2] = (short)(p0.z >> 16);
      a[3] = (short)(p0.w & 0xffff); b[3] = (short)(p0.w >> 16);
      a[4] = (short)(p1.x & 0xffff); b[4] = (short)(p1.x >> 16);
      a[5] = (short)(p1.y & 0xffff); b[5] = (short)(p1.y >> 16);
      a[6] = (short)(p1.z & 0xffff); b[6] = (short)(p1.z >> 16);
      a[7] = (short)(p1.w & 0xffff); b[7] = (short)(p1.w >> 16);
      qh[kc] = a; ql[kc] = b;
    }
  }

  f32x4 acc[16];
#pragma unroll
  for (int od = 0; od < 16; ++od) acc[od] = z4;
  float lsum[4];
#pragma unroll
  for (int r = 0; r < 4; ++r) lsum[r] = 0.f;

  const int qrow_g = qt * 64 + wid * 16 + quad * 4;
  const __hip_bfloat16* kbase = Ksw + (long)kvh * 1048576;  // 128 tiles * 8192
  const __hip_bfloat16* vbase = Vsw + (long)kvh * 1048576;

#pragma unroll
  for (int i = 0; i < 4; ++i) {
    int m = i * 4 + wid;
    async16(kbase + m * 512 + lane * 8, Ks + m * 512 + lane * 8);
    async16(vbase + m * 512 + lane * 8, Vs + m * 512 + lane * 8);
  }
  __syncthreads();  // drain K(0), V(0)

  for (int kt = 0; kt < nt; ++kt) {
    const bool skip = (kt == nt - 1) && (wid < 2);
    f32x4 s[2];
    s[0] = z4; s[1] = z4;
    if (!skip) {
      __builtin_amdgcn_s_setprio(1);
#pragma unroll
      for (int kc = 0; kc < 8; ++kc) {
        bf16x8 ah = qh[kc], al = ql[kc];
#pragma unroll
        for (int ni = 0; ni < 2; ++ni) {
          bf16x8 b = *(const bf16x8*)(Ks + (kc * 4 + quad) * 256 + (ni * 16 + lo) * 8);
          s[ni] = MFMA16(ah, b, s[ni]);
          s[ni] = MFMA16(al, b, s[ni]);
        }
      }
      __builtin_amdgcn_s_setprio(0);
    }
    __syncthreads();  // B: Ks(kt) reads done; drains V(kt) prefetch
    if (kt + 1 < nt) {
      const __hip_bfloat16* kb = kbase + (long)(kt + 1) * 8192;
#pragma unroll
      for (int i = 0; i < 4; ++i) {
        int m = i * 4 + wid;
        async16(kb + m * 512 + lane * 8, Ks + m * 512 + lane * 8);
      }
    }
    if (!skip) {
      float sv[2][4];
      if (kt >= nt - 2) {
#pragma unroll
        for (int ni = 0; ni < 2; ++ni) {
          int kcol = kt * 32 + ni * 16 + lo;
#pragma unroll
          for (int r = 0; r < 4; ++r) {
            float e = __expf(fmaf(s[ni][r], ATT_SCALE, -SOFT_M));
            sv[ni][r] = (kcol > qrow_g + r) ? 0.f : e;
          }
        }
      } else {
#pragma unroll
        for (int ni = 0; ni < 2; ++ni)
#pragma unroll
          for (int r = 0; r < 4; ++r)
            sv[ni][r] = __expf(fmaf(s[ni][r], ATT_SCALE, -SOFT_M));
      }
#pragma unroll
      for (int r = 0; r < 4; ++r) lsum[r] += sv[0][r] + sv[1][r];
#pragma unroll
      for (int ni = 0; ni < 2; ++ni)
#pragma unroll
        for (int r = 0; r < 4; ++r)
          myP[(quad * 4 + r) * 40 + ni * 16 + lo] = __float2bfloat16(sv[ni][r]);
      bf16x8 ap = *(const bf16x8*)(myP + lo * 40 + quad * 8);
      __builtin_amdgcn_s_setprio(1);
#pragma unroll
      for (int od = 0; od < 16; ++od) {
        bf16x8 bv = *(const bf16x8*)(Vs + quad * 2048 + (od * 16 + lo) * 8);
        acc[od] = MFMA16(ap, bv, acc[od]);
      }
      __builtin_amdgcn_s_setprio(0);
    }
    __syncthreads();  // C: Vs(kt) reads done; drains K(kt+1) prefetch
    if (kt + 1 < nt) {
      const __hip_bfloat16* vb = vbase + (long)(kt + 1) * 8192;
#pragma unroll
      for (int i = 0; i < 4; ++i) {
        int m = i * 4 + wid;
        async16(vb + m * 512 + lane * 8, Vs + m * 512 + lane * 8);
      }
    }
  }

  float l_r[4];
#pragma unroll
  for (int r = 0; r < 4; ++r) {
    float su = lsum[r];
#pragma unroll
    for (int off = 1; off < 16; off <<= 1) su += __shfl_xor(su, off);
    l_r[r] = su;
  }
#pragma unroll
  for (int od = 0; od < 16; ++od)
#pragma unroll
    for (int r = 0; r < 4; ++r) {
      int trow = qt * 64 + wid * 16 + quad * 4 + r;
      int col = od * 16 + lo;
      long idx = ((long)trow * NH_SZ + h) * 256 + col;
      float g = __bfloat162float(Gt[idx]);
      float sig = 1.0f / (1.0f + expf(-g));
      float v = (acc[od][r] / l_r[r]) * sig;
      Qp[idx] = pack_hilo(v);
    }
}

// ------------------- out GEMM: A packed hi/lo (2-pass), B bf16, fp32 out
// (Proven fastest variant: rounds 6-7 deep-pipeline replacements were slower.)
__global__ __launch_bounds__(256) void gemm_out(const unsigned* __restrict__ Ap,
                                                const __hip_bfloat16* __restrict__ Bt,
                                                float* __restrict__ C,
                                                int M, int N, int K) {
  __shared__ __align__(16) __hip_bfloat16 Ash[128 * 32];
  __shared__ __align__(16) __hip_bfloat16 Asl[128 * 32];
  __shared__ __align__(16) __hip_bfloat16 Bs[128 * 32];
  const int tid = threadIdx.x;
  const int wid = tid >> 6, lane = tid & 63;
  const int lo = lane & 15, quad = lane >> 4;
  const int wq = blockIdx.x + blockIdx.y * 16;   // nwg = 512
  const int xcd = wq & 7, idx = wq >> 3;         // idx in [0,64)
  const long n0 = (long)(xcd * 2 + (idx & 1)) * 128;
  const long m0 = (long)(idx >> 1) * 128;
  const int wm = (wid >> 1) * 64, wn = (wid & 1) * 64;
  const f32x4 z4 = {0.f, 0.f, 0.f, 0.f};
  f32x4 acc[4][4];
#pragma unroll
  for (int i = 0; i < 4; ++i)
#pragma unroll
    for (int j = 0; j < 4; ++j) acc[i][j] = z4;

  const int cf0 = tid, cf1 = 256 + tid;
  const int br0 = cf0 >> 2, bc0 = (cf0 & 3) * 8;
  const int br1 = cf1 >> 2, bc1 = (cf1 & 3) * 8;
  const __hip_bfloat16* b0 = Bt + (n0 + br0) * K + bc0;
  const __hip_bfloat16* b1 = Bt + (n0 + br1) * K + bc1;

  for (int k0 = 0; k0 < K; k0 += 32) {
    async16(b0 + k0, Bs + cf0 * 8);
    async16(b1 + k0, Bs + cf1 * 8);
#pragma unroll
    for (int it = 0; it < 4; ++it) {
      int c = it * 256 + tid, row = c >> 3, c4 = (c & 7) * 4;
      uint4 p = *(const uint4*)(Ap + (m0 + row) * K + k0 + c4);
      uint2 wh, wl;
      wh.x = (p.x & 0xffff) | ((p.y & 0xffff) << 16);
      wh.y = (p.z & 0xffff) | ((p.w & 0xffff) << 16);
      wl.x = (p.x >> 16) | (p.y & 0xffff0000u);
      wl.y = (p.z >> 16) | (p.w & 0xffff0000u);
      *(uint2*)(Ash + row * 32 + c4) = wh;
      *(uint2*)(Asl + row * 32 + c4) = wl;
    }
    __syncthreads();
    bf16x8 ah[4], al[4], bf[4];
#pragma unroll
    for (int i = 0; i < 4; ++i) {
      ah[i] = *(const bf16x8*)(Ash + (wm + i * 16 + lo) * 32 + quad * 8);
      al[i] = *(const bf16x8*)(Asl + (wm + i * 16 + lo) * 32 + quad * 8);
      bf[i] = *(const bf16x8*)(Bs + (wn + i * 16 + lo) * 32 + quad * 8);
    }
#pragma unroll
    for (int i = 0; i < 4; ++i)
#pragma unroll
      for (int j = 0; j < 4; ++j) {
        acc[i][j] = MFMA16(ah[i], bf[j], acc[i][j]);
        acc[i][j] = MFMA16(al[i], bf[j], acc[i][j]);
      }
    __syncthreads();
  }
#pragma unroll
  for (int i = 0; i < 4; ++i)
#pragma unroll
    for (int j = 0; j < 4; ++j)
#pragma unroll
      for (int r = 0; r < 4; ++r) {
        long row = m0 + wm + i * 16 + quad * 4 + r;
        long col = n0 + wn + j * 16 + lo;
        C[row * N + col] = acc[i][j][r];
      }
}

// ------------------------------------------------------------------- launcher
extern "C" void kernel_launch(void* const* d_in, const int* in_sizes, int n_in,
                              void* d_out, int out_size, void* d_ws, size_t ws_size,
                              hipStream_t stream) {
  (void)in_sizes; (void)n_in; (void)out_size; (void)ws_size;
  const int* positions = (const int*)d_in[0];
  const float* hidden = (const float*)d_in[1];
  const float* Wq = (const float*)d_in[2];
  const float* Wk = (const float*)d_in[3];
  const float* Wv = (const float*)d_in[4];
  const float* Wo = (const float*)d_in[5];
  const float* qw = (const float*)d_in[6];
  const float* kw = (const float*)d_in[7];
  float* out = (float*)d_out;
  char* ws = (char*)d_ws;

  // layout (bytes), total exactly 160 MiB:
  __hip_bfloat16* hid  = (__hip_bfloat16*)(ws + 0);           // 16 MB (dead after GEMMs)
  __hip_bfloat16* WqT  = (__hip_bfloat16*)(ws + 16777216);    // 32 MB
  __hip_bfloat16* WkT  = (__hip_bfloat16*)(ws + 50331648);    //  2 MB  (WvT contiguous after)
  __hip_bfloat16* WvT  = (__hip_bfloat16*)(ws + 52428800);    //  2 MB
  float*          qf   = (float*)(ws + 54525952);             // 64 MB region: packed q/o
  __hip_bfloat16* gate = (__hip_bfloat16*)(ws + 121634816);   // 32 MB (T,16,256)
  float*          kf   = (float*)(ws + 155189248);            //  8 MB (T,2,256) fp32
  __hip_bfloat16* vraw = (__hip_bfloat16*)(ws + 163577856);   //  4 MB -> end 167,772,160
  __hip_bfloat16* Ksw  = WkT;                                  // alias 4 MB [WkT+WvT] after kv GEMM
  __hip_bfloat16* Vsw  = hid;                                  // alias 4 MB of hid after GEMMs
  __hip_bfloat16* WoT  = gate;                                 // alias gate region after attn
  unsigned* qpk = (unsigned*)qf;
  float2*   tab = (float2*)out;   // 1 MB RoPE table in d_out scratch (dead
                                  // until gemm_out fully overwrites d_out)

  // 0) RoPE cos/sin table (needed by gemm_qg2 epilogue + norm_rope_k)
  rope_table<<<dim3(512), dim3(256), 0, stream>>>(positions, tab);
  // 1) casts / transposes
  cast_f32_bf16<<<dim3(8192), dim3(256), 0, stream>>>(hidden, hid, 2097152);
  transpose_cast<float><<<dim3(256, 64), dim3(256), 0, stream>>>(Wq, WqT, 2048, 8192);
  transpose_cast<float><<<dim3(16, 64), dim3(256), 0, stream>>>(Wk, WkT, 2048, 512);
  transpose_cast<float><<<dim3(16, 64), dim3(256), 0, stream>>>(Wv, WvT, 2048, 512);
  // 2) projections: q packed+RoPE'd directly (fused, table trig) + gate; k/v
  gemm_qg2<<<dim3(8, 64), dim3(512), 0, stream>>>(hid, WqT, qpk, gate, tab, qw);
  gemm_kv<<<dim3(8, 32), dim3(256), 0, stream>>>(hid, WkT, kf, vraw, 4096, 1024, 2048);
  // 3) V -> swizzled (after GEMMs: Vsw aliases hid)
  v_swizzle<<<dim3(64, 2), dim3(256), 0, stream>>>(vraw, Vsw);
  // 4) K-only RMSNorm + RoPE(table) -> swizzled Ksw
  norm_rope_k<<<dim3(2048), dim3(256), 0, stream>>>(kf, Ksw, tab, kw);
  // 5) flash attention, one q-tile per block, big-first + XCD swizzle
  attn_kernel<<<dim3(64, 16), dim3(256), 0, stream>>>(qpk, Ksw, Vsw, gate);
  // 6) Wo -> bf16 transpose (into dead gate region), then 2-pass out GEMM
  //    (overwrites d_out fully, including the table scratch)
  transpose_cast<float><<<dim3(64, 128), dim3(256), 0, stream>>>(Wo, WoT, 4096, 2048);
  gemm_out<<<dim3(16, 32), dim3(256), 0, stream>>>(qpk, WoT, out, 4096, 2048, 4096);
}